// Round 1
// baseline (381.594 us; speedup 1.0000x reference)
//
#include <hip/hip_runtime.h>
#include <math.h>

#define B 64
#define N 256
#define C 512

// guide modality for module m = 3*mi + j
__device__ __forceinline__ int guide_of(int m) {
    int mi = m / 3, j = m % 3;
    return (j == 0) ? mi : (j == 1 ? ((mi == 0) ? 1 : 0) : ((mi == 2) ? 1 : 2));
}

template<int NW>
__device__ __forceinline__ float breduce_sum(float v, volatile float* red, int t) {
    int w = t >> 6, l = t & 63;
#pragma unroll
    for (int mm = 1; mm < 64; mm <<= 1) v += __shfl_xor(v, mm);
    __syncthreads();
    if (l == 0) red[w] = v;
    __syncthreads();
    float s = red[0];
#pragma unroll
    for (int i = 1; i < NW; i++) s += red[i];
    return s;
}

template<int NW>
__device__ __forceinline__ float breduce_max(float v, volatile float* red, int t) {
    int w = t >> 6, l = t & 63;
#pragma unroll
    for (int mm = 1; mm < 64; mm <<= 1) v = fmaxf(v, __shfl_xor(v, mm));
    __syncthreads();
    if (l == 0) red[w] = v;
    __syncthreads();
    float s = red[0];
#pragma unroll
    for (int i = 1; i < NW; i++) s = fmaxf(s, red[i]);
    return s;
}

// gn[g][b][:] = g / max(||g||, 1e-8)
__global__ __launch_bounds__(64) void k_gnorm(const float* g0, const float* g1, const float* g2,
                                              float* gn) {
    int gm = blockIdx.y, b = blockIdx.x, l = threadIdx.x;
    const float* g = (gm == 0) ? g0 : (gm == 1 ? g1 : g2);
    const float4* gv = (const float4*)(g + (size_t)b * C);
    float4 a = gv[l], bb = gv[64 + l];
    float pp = a.x * a.x + a.y * a.y + a.z * a.z + a.w * a.w +
               bb.x * bb.x + bb.y * bb.y + bb.z * bb.z + bb.w * bb.w;
#pragma unroll
    for (int mm = 1; mm < 64; mm <<= 1) pp += __shfl_xor(pp, mm);
    float inv = 1.0f / fmaxf(sqrtf(pp), 1e-8f);
    float4* o = (float4*)(gn + ((size_t)gm * B + b) * C);
    a.x *= inv; a.y *= inv; a.z *= inv; a.w *= inv;
    bb.x *= inv; bb.y *= inv; bb.z *= inv; bb.w *= inv;
    o[l] = a; o[64 + l] = bb;
}

// q[m][b][c] = sum_e g_guide[b,e] * qw[m,e,c] + qb[m,c]
__global__ __launch_bounds__(256) void k_qproj(const float* g0, const float* g1, const float* g2,
                                               const float* qw, const float* qb, float* q) {
    int m = blockIdx.y;
    int c0 = blockIdx.x * 64;
    int t = threadIdx.x;
    int gi = guide_of(m);
    const float* g = (gi == 0) ? g0 : (gi == 1 ? g1 : g2);
    __shared__ float tile[64][64];
    int c = c0 + (t & 63);
    int br = (t >> 6) * 16;
    float acc[16];
    float bias = qb[m * C + c];
#pragma unroll
    for (int i = 0; i < 16; i++) acc[i] = bias;
    for (int e0 = 0; e0 < C; e0 += 64) {
        __syncthreads();
        for (int idx = t; idx < 64 * 64; idx += 256)
            tile[idx >> 6][idx & 63] = g[(size_t)(idx >> 6) * C + e0 + (idx & 63)];
        __syncthreads();
        for (int e = 0; e < 64; e++) {
            float wv = qw[(size_t)m * C * C + (size_t)(e0 + e) * C + c];
#pragma unroll
            for (int i = 0; i < 16; i++) acc[i] += tile[br + i][e] * wv;
        }
    }
#pragma unroll
    for (int i = 0; i < 16; i++) q[((size_t)m * B + br + i) * C + c] = acc[i];
}

// qk[m][b][c] = sum_d kw[m,c,d] * q[m,b,d] ; qkb[m][b] = sum_d kb[m,d]*q[m,b,d]
__global__ __launch_bounds__(256) void k_kproj(const float* kw, const float* kb,
                                               const float* q, float* qk, float* qkb) {
    int m = blockIdx.y;
    int c0 = blockIdx.x * 64;
    int t = threadIdx.x;
    __shared__ float kt[64][65];
    __shared__ float qt[64][65];
    int c = t & 63;
    int br = (t >> 6) * 16;
    float acc[16];
#pragma unroll
    for (int i = 0; i < 16; i++) acc[i] = 0.f;
    for (int d0 = 0; d0 < C; d0 += 64) {
        __syncthreads();
        for (int idx = t; idx < 4096; idx += 256) {
            int r = idx >> 6, cc = idx & 63;
            kt[r][cc] = kw[(size_t)m * C * C + (size_t)(c0 + r) * C + d0 + cc];
            qt[r][cc] = q[((size_t)m * B + r) * C + d0 + cc];
        }
        __syncthreads();
        for (int d = 0; d < 64; d++) {
            float kv = kt[c][d];
#pragma unroll
            for (int i = 0; i < 16; i++) acc[i] += kv * qt[br + i][d];
        }
    }
#pragma unroll
    for (int i = 0; i < 16; i++) qk[((size_t)m * B + br + i) * C + c0 + c] = acc[i];
    if (blockIdx.x == 0) {
        __syncthreads();
        if (t < B) {
            float s = 0.f;
            for (int d = 0; d < C; d++) s += kb[m * C + d] * q[((size_t)m * B + t) * C + d];
            qkb[m * B + t] = s;
        }
    }
}

// per (mi,b): gcat -> fc1 -> LN -> gelu -> fc2 -> gelu -> fc3 -> softmax -> wmix
__global__ __launch_bounds__(256) void k_mlp(const float* g0, const float* g1, const float* g2,
                                             const float* w1, const float* b1,
                                             const float* lng, const float* lnb,
                                             const float* w2, const float* b2,
                                             const float* w3, const float* b3, float* wmix) {
    int mi = blockIdx.y, b = blockIdx.x, t = threadIdx.x;
    __shared__ float gc[1536];
    __shared__ float h1[256];
    __shared__ float h2[64];
    __shared__ float red[4];
    for (int idx = t; idx < 1536; idx += 256) {
        const float* g = (idx < 512) ? g0 : (idx < 1024 ? g1 : g2);
        gc[idx] = g[(size_t)b * C + (idx & 511)];
    }
    __syncthreads();
    float acc = b1[mi * 256 + t];
    const float* W1 = w1 + (size_t)mi * 1536 * 256;
    for (int e = 0; e < 1536; e++) acc += gc[e] * W1[(size_t)e * 256 + t];
    // layernorm over 256
    float total = breduce_sum<4>(acc, red, t);
    float mean = total * (1.0f / 256.0f);
    float dv = acc - mean;
    float vtot = breduce_sum<4>(dv * dv, red, t);
    float var = vtot * (1.0f / 256.0f);
    float x = dv / sqrtf(var + 1e-5f) * lng[mi * 256 + t] + lnb[mi * 256 + t];
    x = 0.5f * x * (1.0f + erff(x * 0.70710678118654752f));
    h1[t] = x;
    __syncthreads();
    if (t < 64) {
        float a2 = b2[mi * 64 + t];
        const float* W2 = w2 + (size_t)mi * 256 * 64;
        for (int e = 0; e < 256; e++) a2 += h1[e] * W2[e * 64 + t];
        a2 = 0.5f * a2 * (1.0f + erff(a2 * 0.70710678118654752f));
        h2[t] = a2;
    }
    __syncthreads();
    if (t == 0) {
        float l3[3];
        for (int j = 0; j < 3; j++) {
            float a3 = b3[mi * 3 + j];
            for (int e = 0; e < 64; e++) a3 += h2[e] * w3[((size_t)mi * 64 + e) * 3 + j];
            l3[j] = a3;
        }
        float mx = fmaxf(l3[0], fmaxf(l3[1], l3[2]));
        float e0 = expf(l3[0] - mx), e1 = expf(l3[1] - mx), e2 = expf(l3[2] - mx);
        float inv = 1.0f / (e0 + e1 + e2);
        wmix[((size_t)mi * B + b) * 4 + 0] = e0 * inv;
        wmix[((size_t)mi * B + b) * 4 + 1] = e1 * inv;
        wmix[((size_t)mi * B + b) * 4 + 2] = e2 * inv;
    }
}

__device__ __forceinline__ float dot4(float4 a, float4 b) {
    return a.x * b.x + a.y * b.y + a.z * b.z + a.w * b.w;
}

// main: per (mi,b) block -> logits -> softmax -> zscore+sigmoid -> mix -> quantile -> mask -> scale
__global__ __launch_bounds__(512) void k_main(const float* p0, const float* p1, const float* p2,
                                              const float* qk, const float* qkb, const float* gn,
                                              const float* wmix, float* out) {
    int mi = blockIdx.y, b = blockIdx.x;
    int t = threadIdx.x, w = t >> 6, l = t & 63;
    const float* p = (mi == 0) ? p0 : (mi == 1 ? p1 : p2);
    __shared__ float lgt[3][256];
    __shared__ float sc[256];
    __shared__ float msk[256];
    __shared__ float red[8];
    __shared__ float thr_s;

    float4 qa[3], qb_[3], ga[3], gb_[3];
    float qkbv[3];
#pragma unroll
    for (int j = 0; j < 3; j++) {
        int m = 3 * mi + j;
        int gi = guide_of(m);
        const float4* qv = (const float4*)(qk + ((size_t)m * B + b) * C);
        qa[j] = qv[l]; qb_[j] = qv[64 + l];
        const float4* gv = (const float4*)(gn + ((size_t)gi * B + b) * C);
        ga[j] = gv[l]; gb_[j] = gv[64 + l];
        qkbv[j] = qkb[m * B + b];
    }
    const float4* pbase = (const float4*)(p + (size_t)b * N * C);
    const float SCALE = 0.044194173824159216f;  // 512^-0.5

    for (int n = w; n < N; n += 8) {
        float4 pa = pbase[(size_t)n * 128 + l];
        float4 pb = pbase[(size_t)n * 128 + 64 + l];
        float pp = dot4(pa, pa) + dot4(pb, pb);
        float dj[3], cj[3];
#pragma unroll
        for (int j = 0; j < 3; j++) {
            dj[j] = dot4(pa, qa[j]) + dot4(pb, qb_[j]);
            cj[j] = dot4(pa, ga[j]) + dot4(pb, gb_[j]);
        }
#pragma unroll
        for (int mm = 1; mm < 64; mm <<= 1) {
            pp += __shfl_xor(pp, mm);
#pragma unroll
            for (int j = 0; j < 3; j++) {
                dj[j] += __shfl_xor(dj[j], mm);
                cj[j] += __shfl_xor(cj[j], mm);
            }
        }
        if (l == 0) {
            float rn = fmaxf(sqrtf(pp), 1e-8f);
#pragma unroll
            for (int j = 0; j < 3; j++)
                lgt[j][n] = (dj[j] + qkbv[j]) * SCALE + (cj[j] / rn) * (1.0f / 0.3f);
        }
    }
    __syncthreads();

    float w0 = wmix[((size_t)mi * B + b) * 4 + 0];
    float w1v = wmix[((size_t)mi * B + b) * 4 + 1];
    float w2v = wmix[((size_t)mi * B + b) * 4 + 2];
    float wj[3] = {w0, w1v, w2v};
    float score = 0.f;
    for (int j = 0; j < 3; j++) {
        float v = (t < N) ? lgt[j][t] : -1e30f;
        float mx = breduce_max<8>(v, red, t);
        float e = (t < N) ? expf(v - mx) : 0.f;
        float s = breduce_sum<8>(e, red, t);
        float pr = e / s;
        float total = breduce_sum<8>((t < N) ? pr : 0.f, red, t);
        float mean = total * (1.0f / 256.0f);
        float dv = (t < N) ? (pr - mean) : 0.f;
        float vtot = breduce_sum<8>(dv * dv, red, t);
        float sd = sqrtf(vtot * (1.0f / 255.0f)) + 1e-5f;
        float z = dv / sd;
        float sg = 1.0f / (1.0f + expf(-z));
        score += wj[j] * sg;
    }
    if (t < N) sc[t] = score;
    __syncthreads();
    if (t < N) {
        int cl = 0, ce = 0;
        for (int m2 = 0; m2 < N; m2++) {
            float v2 = sc[m2];
            cl += (v2 < score) ? 1 : 0;
            ce += (v2 == score) ? 1 : 0;
        }
        if (cl <= 102 && 102 < cl + ce) thr_s = score;
    }
    __syncthreads();
    float thr = thr_s;
    if (t < N) {
        float mk = 1.0f / (1.0f + expf(-(score - thr) * (1.0f / 0.3f)));
        msk[t] = mk;
        out[(size_t)3 * B * N * C + ((size_t)mi * B + b) * N + t] = mk;
    }
    __syncthreads();
    float4* o4 = (float4*)(out + (size_t)mi * B * N * C + (size_t)b * N * C);
    for (int idx = t; idx < N * C / 4; idx += 512) {
        float4 v = pbase[idx];
        float mkv = msk[idx >> 7];
        v.x *= mkv; v.y *= mkv; v.z *= mkv; v.w *= mkv;
        o4[idx] = v;
    }
}

extern "C" void kernel_launch(void* const* d_in, const int* in_sizes, int n_in,
                              void* d_out, int out_size, void* d_ws, size_t ws_size,
                              hipStream_t stream) {
    const float* rgb   = (const float*)d_in[0];
    const float* nir   = (const float*)d_in[1];
    const float* tir   = (const float*)d_in[2];
    const float* rgb_g = (const float*)d_in[3];
    const float* nir_g = (const float*)d_in[4];
    const float* tir_g = (const float*)d_in[5];
    const float* attn_qw = (const float*)d_in[6];
    const float* attn_qb = (const float*)d_in[7];
    const float* attn_kw = (const float*)d_in[8];
    const float* attn_kb = (const float*)d_in[9];
    const float* mlp_w1 = (const float*)d_in[10];
    const float* mlp_b1 = (const float*)d_in[11];
    const float* ln_g = (const float*)d_in[12];
    const float* ln_b = (const float*)d_in[13];
    const float* mlp_w2 = (const float*)d_in[14];
    const float* mlp_b2 = (const float*)d_in[15];
    const float* mlp_w3 = (const float*)d_in[16];
    const float* mlp_b3 = (const float*)d_in[17];
    float* out = (float*)d_out;

    float* ws = (float*)d_ws;
    float* q    = ws;                   // 9*64*512 = 294912
    float* qk   = ws + 294912;          // 294912
    float* qkb  = ws + 589824;          // 576 (pad to 1024)
    float* gn   = ws + 590848;          // 3*64*512 = 98304
    float* wmix = ws + 689152;          // 3*64*4 = 768

    k_gnorm<<<dim3(B, 3), 64, 0, stream>>>(rgb_g, nir_g, tir_g, gn);
    k_qproj<<<dim3(8, 9), 256, 0, stream>>>(rgb_g, nir_g, tir_g, attn_qw, attn_qb, q);
    k_kproj<<<dim3(8, 9), 256, 0, stream>>>(attn_kw, attn_kb, q, qk, qkb);
    k_mlp<<<dim3(B, 3), 256, 0, stream>>>(rgb_g, nir_g, tir_g, mlp_w1, mlp_b1, ln_g, ln_b,
                                          mlp_w2, mlp_b2, mlp_w3, mlp_b3, wmix);
    k_main<<<dim3(B, 3), 512, 0, stream>>>(rgb, nir, tir, qk, qkb, gn, wmix, out);
}

// Round 2
// 168.242 us; speedup vs baseline: 2.2681x; 2.2681x over previous
//
#include <hip/hip_runtime.h>
#include <math.h>

#define B 64
#define N 256
#define C 512

// guide modality for module m = 3*mi + j
__device__ __forceinline__ int guide_of(int m) {
    int mi = m / 3, j = m % 3;
    return (j == 0) ? mi : (j == 1 ? ((mi == 0) ? 1 : 0) : ((mi == 2) ? 1 : 2));
}

template<int NW>
__device__ __forceinline__ float breduce_sum(float v, volatile float* red, int t) {
    int w = t >> 6, l = t & 63;
#pragma unroll
    for (int mm = 1; mm < 64; mm <<= 1) v += __shfl_xor(v, mm);
    __syncthreads();
    if (l == 0) red[w] = v;
    __syncthreads();
    float s = red[0];
#pragma unroll
    for (int i = 1; i < NW; i++) s += red[i];
    return s;
}

template<int NW>
__device__ __forceinline__ float breduce_max(float v, volatile float* red, int t) {
    int w = t >> 6, l = t & 63;
#pragma unroll
    for (int mm = 1; mm < 64; mm <<= 1) v = fmaxf(v, __shfl_xor(v, mm));
    __syncthreads();
    if (l == 0) red[w] = v;
    __syncthreads();
    float s = red[0];
#pragma unroll
    for (int i = 1; i < NW; i++) s = fmaxf(s, red[i]);
    return s;
}

// gn[g][b][:] = g / max(||g||, 1e-8)
__global__ __launch_bounds__(64) void k_gnorm(const float* g0, const float* g1, const float* g2,
                                              float* gn) {
    int gm = blockIdx.y, b = blockIdx.x, l = threadIdx.x;
    const float* g = (gm == 0) ? g0 : (gm == 1 ? g1 : g2);
    const float4* gv = (const float4*)(g + (size_t)b * C);
    float4 a = gv[l], bb = gv[64 + l];
    float pp = a.x * a.x + a.y * a.y + a.z * a.z + a.w * a.w +
               bb.x * bb.x + bb.y * bb.y + bb.z * bb.z + bb.w * bb.w;
#pragma unroll
    for (int mm = 1; mm < 64; mm <<= 1) pp += __shfl_xor(pp, mm);
    float inv = 1.0f / fmaxf(sqrtf(pp), 1e-8f);
    float4* o = (float4*)(gn + ((size_t)gm * B + b) * C);
    a.x *= inv; a.y *= inv; a.z *= inv; a.w *= inv;
    bb.x *= inv; bb.y *= inv; bb.z *= inv; bb.w *= inv;
    o[l] = a; o[64 + l] = bb;
}

// Stage A of q-projection, K-split:
// part[ks][m][b][c] = sum_{e in slice ks} g_guide[b,e] * qw[m,e,c]
// grid (cx=8, m=9, ks=8), 256 threads
__global__ __launch_bounds__(256) void k_qprojA(const float* g0, const float* g1, const float* g2,
                                                const float* qw, float* part) {
    int cx = blockIdx.x, m = blockIdx.y, ks = blockIdx.z;
    int t = threadIdx.x;
    int c0 = cx * 64, e0 = ks * 64;
    int gi = guide_of(m);
    const float* g = (gi == 0) ? g0 : (gi == 1 ? g1 : g2);
    __shared__ float gt[64][64];  // [b][e]
    for (int idx = t; idx < 4096; idx += 256)
        gt[idx >> 6][idx & 63] = g[(size_t)(idx >> 6) * C + e0 + (idx & 63)];
    __syncthreads();
    int c = c0 + (t & 63);
    int br = (t >> 6) * 16;
    float acc[16];
#pragma unroll
    for (int i = 0; i < 16; i++) acc[i] = 0.f;
    const float* W = qw + (size_t)m * C * C + (size_t)e0 * C + c;
#pragma unroll 4
    for (int e = 0; e < 64; e++) {
        float wv = W[(size_t)e * C];
#pragma unroll
        for (int i = 0; i < 16; i++) acc[i] += gt[br + i][e] * wv;
    }
#pragma unroll
    for (int i = 0; i < 16; i++)
        part[(size_t)ks * 294912 + ((size_t)m * B + br + i) * C + c] = acc[i];
}

// q[i] = sum_ks part[ks][i] + qb broadcast
__global__ __launch_bounds__(256) void k_qreduce(const float* part, const float* qb, float* q) {
    int i = blockIdx.x * 256 + threadIdx.x;  // 294912 total
    float s = 0.f;
#pragma unroll
    for (int ks = 0; ks < 8; ks++) s += part[(size_t)ks * 294912 + i];
    int c = i & 511;
    int m = i >> 15;  // / (B*C)
    q[i] = s + qb[m * C + c];
}

// Stage A of k-projection (transposed weight), K-split:
// part[ds][m][b][c] = sum_{d in slice ds} kw[m,c,d] * q[m,b,d]
__global__ __launch_bounds__(256) void k_kprojA(const float* kw, const float* q, float* part) {
    int cx = blockIdx.x, m = blockIdx.y, ds = blockIdx.z;
    int t = threadIdx.x;
    int c0 = cx * 64, d0 = ds * 64;
    __shared__ float kt[64][65];  // [c][d], padded
    __shared__ float qt[64][64];  // [b][d]
    for (int idx = t; idx < 4096; idx += 256) {
        int r = idx >> 6, cc = idx & 63;
        kt[r][cc] = kw[((size_t)m * C + c0 + r) * C + d0 + cc];
        qt[r][cc] = q[((size_t)m * B + r) * C + d0 + cc];
    }
    __syncthreads();
    int c = t & 63;
    int br = (t >> 6) * 16;
    float acc[16];
#pragma unroll
    for (int i = 0; i < 16; i++) acc[i] = 0.f;
#pragma unroll 4
    for (int d = 0; d < 64; d++) {
        float kv = kt[c][d];
#pragma unroll
        for (int i = 0; i < 16; i++) acc[i] += kv * qt[br + i][d];
    }
#pragma unroll
    for (int i = 0; i < 16; i++)
        part[(size_t)ds * 294912 + ((size_t)m * B + br + i) * C + c0 + c] = acc[i];
}

__global__ __launch_bounds__(256) void k_kreduce(const float* part, float* qk) {
    int i = blockIdx.x * 256 + threadIdx.x;
    float s = 0.f;
#pragma unroll
    for (int ks = 0; ks < 8; ks++) s += part[(size_t)ks * 294912 + i];
    qk[i] = s;
}

// qkb[m][b] = q[m,b,:] . kb[m,:]
__global__ __launch_bounds__(64) void k_qkb(const float* q, const float* kb, float* qkb) {
    int b = blockIdx.x, m = blockIdx.y, l = threadIdx.x;
    const float4* qv = (const float4*)(q + ((size_t)m * B + b) * C);
    const float4* kv = (const float4*)(kb + (size_t)m * C);
    float4 a = qv[l], bb = qv[64 + l];
    float4 c = kv[l], d = kv[64 + l];
    float s = a.x * c.x + a.y * c.y + a.z * c.z + a.w * c.w +
              bb.x * d.x + bb.y * d.y + bb.z * d.z + bb.w * d.w;
#pragma unroll
    for (int mm = 1; mm < 64; mm <<= 1) s += __shfl_xor(s, mm);
    if (l == 0) qkb[m * B + b] = s;
}

// per (mi,b): gcat -> fc1 -> LN -> gelu -> fc2 -> gelu -> fc3 -> softmax -> wmix
__global__ __launch_bounds__(512) void k_mlp(const float* g0, const float* g1, const float* g2,
                                             const float* w1, const float* b1,
                                             const float* lng, const float* lnb,
                                             const float* w2, const float* b2,
                                             const float* w3, const float* b3, float* wmix) {
    int mi = blockIdx.y, b = blockIdx.x, t = threadIdx.x;
    __shared__ float gc[1536];
    __shared__ float h1p[2][256];
    __shared__ float h1[256];
    __shared__ float h2p[8][64];
    __shared__ float h2[64];
    __shared__ float red[8];
    for (int idx = t; idx < 1536; idx += 512) {
        const float* g = (idx < 512) ? g0 : (idx < 1024 ? g1 : g2);
        gc[idx] = g[(size_t)b * C + (idx & 511)];
    }
    __syncthreads();
    {
        int col = t & 255, half = t >> 8;
        float acc = 0.f;
        const float* W1 = w1 + (size_t)mi * 1536 * 256 + (size_t)half * 768 * 256 + col;
        const float* gch = gc + half * 768;
#pragma unroll 8
        for (int e = 0; e < 768; e++) acc += gch[e] * W1[(size_t)e * 256];
        h1p[half][col] = acc;
    }
    __syncthreads();
    float a1 = 0.f;
    if (t < 256) a1 = h1p[0][t] + h1p[1][t] + b1[mi * 256 + t];
    // layernorm over 256 (512 threads participate, inactive contribute 0)
    float total = breduce_sum<8>((t < 256) ? a1 : 0.f, red, t);
    float mean = total * (1.0f / 256.0f);
    float dv = (t < 256) ? (a1 - mean) : 0.f;
    float vtot = breduce_sum<8>(dv * dv, red, t);
    float var = vtot * (1.0f / 256.0f);
    if (t < 256) {
        float x = dv / sqrtf(var + 1e-5f) * lng[mi * 256 + t] + lnb[mi * 256 + t];
        x = 0.5f * x * (1.0f + erff(x * 0.70710678118654752f));
        h1[t] = x;
    }
    __syncthreads();
    {
        int col = t & 63, sl = t >> 6;  // 8 slices of 32
        float a2 = 0.f;
        const float* W2 = w2 + (size_t)mi * 256 * 64 + col;
#pragma unroll 8
        for (int e = sl * 32; e < sl * 32 + 32; e++) a2 += h1[e] * W2[(size_t)e * 64];
        h2p[sl][col] = a2;
    }
    __syncthreads();
    if (t < 64) {
        float a2 = b2[mi * 64 + t];
#pragma unroll
        for (int s2 = 0; s2 < 8; s2++) a2 += h2p[s2][t];
        a2 = 0.5f * a2 * (1.0f + erff(a2 * 0.70710678118654752f));
        h2[t] = a2;
    }
    __syncthreads();
    if (t == 0) {
        float l3[3];
        for (int j = 0; j < 3; j++) {
            float a3 = b3[mi * 3 + j];
            for (int e = 0; e < 64; e++) a3 += h2[e] * w3[((size_t)mi * 64 + e) * 3 + j];
            l3[j] = a3;
        }
        float mx = fmaxf(l3[0], fmaxf(l3[1], l3[2]));
        float e0 = expf(l3[0] - mx), e1 = expf(l3[1] - mx), e2 = expf(l3[2] - mx);
        float inv = 1.0f / (e0 + e1 + e2);
        wmix[((size_t)mi * B + b) * 4 + 0] = e0 * inv;
        wmix[((size_t)mi * B + b) * 4 + 1] = e1 * inv;
        wmix[((size_t)mi * B + b) * 4 + 2] = e2 * inv;
    }
}

__device__ __forceinline__ float dot4(float4 a, float4 b) {
    return a.x * b.x + a.y * b.y + a.z * b.z + a.w * b.w;
}

// main: per (mi,b) block -> logits -> softmax -> zscore+sigmoid -> mix -> quantile -> mask -> scale
__global__ __launch_bounds__(512) void k_main(const float* p0, const float* p1, const float* p2,
                                              const float* qk, const float* qkb, const float* gn,
                                              const float* wmix, float* out) {
    int mi = blockIdx.y, b = blockIdx.x;
    int t = threadIdx.x, w = t >> 6, l = t & 63;
    const float* p = (mi == 0) ? p0 : (mi == 1 ? p1 : p2);
    __shared__ float lgt[3][256];
    __shared__ float sc[256];
    __shared__ float msk[256];
    __shared__ float red[8];
    __shared__ float thr_s;

    float4 qa[3], qb_[3], ga[3], gb_[3];
    float qkbv[3];
#pragma unroll
    for (int j = 0; j < 3; j++) {
        int m = 3 * mi + j;
        int gi = guide_of(m);
        const float4* qv = (const float4*)(qk + ((size_t)m * B + b) * C);
        qa[j] = qv[l]; qb_[j] = qv[64 + l];
        const float4* gv = (const float4*)(gn + ((size_t)gi * B + b) * C);
        ga[j] = gv[l]; gb_[j] = gv[64 + l];
        qkbv[j] = qkb[m * B + b];
    }
    const float4* pbase = (const float4*)(p + (size_t)b * N * C);
    const float SCALE = 0.044194173824159216f;  // 512^-0.5

    for (int n = w; n < N; n += 8) {
        float4 pa = pbase[(size_t)n * 128 + l];
        float4 pb = pbase[(size_t)n * 128 + 64 + l];
        float pp = dot4(pa, pa) + dot4(pb, pb);
        float dj[3], cj[3];
#pragma unroll
        for (int j = 0; j < 3; j++) {
            dj[j] = dot4(pa, qa[j]) + dot4(pb, qb_[j]);
            cj[j] = dot4(pa, ga[j]) + dot4(pb, gb_[j]);
        }
#pragma unroll
        for (int mm = 1; mm < 64; mm <<= 1) {
            pp += __shfl_xor(pp, mm);
#pragma unroll
            for (int j = 0; j < 3; j++) {
                dj[j] += __shfl_xor(dj[j], mm);
                cj[j] += __shfl_xor(cj[j], mm);
            }
        }
        if (l == 0) {
            float rn = fmaxf(sqrtf(pp), 1e-8f);
#pragma unroll
            for (int j = 0; j < 3; j++)
                lgt[j][n] = (dj[j] + qkbv[j]) * SCALE + (cj[j] / rn) * (1.0f / 0.3f);
        }
    }
    __syncthreads();

    float w0 = wmix[((size_t)mi * B + b) * 4 + 0];
    float w1v = wmix[((size_t)mi * B + b) * 4 + 1];
    float w2v = wmix[((size_t)mi * B + b) * 4 + 2];
    float wj[3] = {w0, w1v, w2v};
    float score = 0.f;
    for (int j = 0; j < 3; j++) {
        float v = (t < N) ? lgt[j][t] : -1e30f;
        float mx = breduce_max<8>(v, red, t);
        float e = (t < N) ? expf(v - mx) : 0.f;
        float s = breduce_sum<8>(e, red, t);
        float pr = e / s;
        float total = breduce_sum<8>((t < N) ? pr : 0.f, red, t);
        float mean = total * (1.0f / 256.0f);
        float dv = (t < N) ? (pr - mean) : 0.f;
        float vtot = breduce_sum<8>(dv * dv, red, t);
        float sd = sqrtf(vtot * (1.0f / 255.0f)) + 1e-5f;
        float z = dv / sd;
        float sg = 1.0f / (1.0f + expf(-z));
        score += wj[j] * sg;
    }
    if (t < N) sc[t] = score;
    __syncthreads();
    if (t < N) {
        int cl = 0, ce = 0;
        for (int m2 = 0; m2 < N; m2++) {
            float v2 = sc[m2];
            cl += (v2 < score) ? 1 : 0;
            ce += (v2 == score) ? 1 : 0;
        }
        if (cl <= 102 && 102 < cl + ce) thr_s = score;
    }
    __syncthreads();
    float thr = thr_s;
    if (t < N) {
        float mk = 1.0f / (1.0f + expf(-(score - thr) * (1.0f / 0.3f)));
        msk[t] = mk;
        out[(size_t)3 * B * N * C + ((size_t)mi * B + b) * N + t] = mk;
    }
    __syncthreads();
    float4* o4 = (float4*)(out + (size_t)mi * B * N * C + (size_t)b * N * C);
    for (int idx = t; idx < N * C / 4; idx += 512) {
        float4 v = pbase[idx];
        float mkv = msk[idx >> 7];
        v.x *= mkv; v.y *= mkv; v.z *= mkv; v.w *= mkv;
        o4[idx] = v;
    }
}

extern "C" void kernel_launch(void* const* d_in, const int* in_sizes, int n_in,
                              void* d_out, int out_size, void* d_ws, size_t ws_size,
                              hipStream_t stream) {
    const float* rgb   = (const float*)d_in[0];
    const float* nir   = (const float*)d_in[1];
    const float* tir   = (const float*)d_in[2];
    const float* rgb_g = (const float*)d_in[3];
    const float* nir_g = (const float*)d_in[4];
    const float* tir_g = (const float*)d_in[5];
    const float* attn_qw = (const float*)d_in[6];
    const float* attn_qb = (const float*)d_in[7];
    const float* attn_kw = (const float*)d_in[8];
    const float* attn_kb = (const float*)d_in[9];
    const float* mlp_w1 = (const float*)d_in[10];
    const float* mlp_b1 = (const float*)d_in[11];
    const float* ln_g = (const float*)d_in[12];
    const float* ln_b = (const float*)d_in[13];
    const float* mlp_w2 = (const float*)d_in[14];
    const float* mlp_b2 = (const float*)d_in[15];
    const float* mlp_w3 = (const float*)d_in[16];
    const float* mlp_b3 = (const float*)d_in[17];
    float* out = (float*)d_out;

    float* ws = (float*)d_ws;
    // layout (floats):
    float* part = ws;                    // 8*294912 = 2359296  (reused by q & k stages)
    float* q    = ws + 2359296;          // 294912
    float* qk   = ws + 2654208;          // 294912
    float* qkb  = ws + 2949120;          // 576 -> pad 1024
    float* gn   = ws + 2950144;          // 98304
    float* wmix = ws + 3048448;          // 768
    // total 3049216 floats = 12.2 MB

    k_gnorm<<<dim3(B, 3), 64, 0, stream>>>(rgb_g, nir_g, tir_g, gn);
    k_qprojA<<<dim3(8, 9, 8), 256, 0, stream>>>(rgb_g, nir_g, tir_g, attn_qw, part);
    k_qreduce<<<1152, 256, 0, stream>>>(part, attn_qb, q);
    k_kprojA<<<dim3(8, 9, 8), 256, 0, stream>>>(attn_kw, q, part);
    k_kreduce<<<1152, 256, 0, stream>>>(part, qk);
    k_qkb<<<dim3(B, 9), 64, 0, stream>>>(q, attn_kb, qkb);
    k_mlp<<<dim3(B, 3), 512, 0, stream>>>(rgb_g, nir_g, tir_g, mlp_w1, mlp_b1, ln_g, ln_b,
                                          mlp_w2, mlp_b2, mlp_w3, mlp_b3, wmix);
    k_main<<<dim3(B, 3), 512, 0, stream>>>(rgb, nir, tir, qk, qkb, gn, wmix, out);
}

// Round 3
// 140.543 us; speedup vs baseline: 2.7151x; 1.1971x over previous
//
#include <hip/hip_runtime.h>
#include <math.h>

#define B 64
#define N 256
#define C 512

// guide modality for module m = 3*mi + j
__device__ __forceinline__ int guide_of(int m) {
    int mi = m / 3, j = m % 3;
    return (j == 0) ? mi : (j == 1 ? ((mi == 0) ? 1 : 0) : ((mi == 2) ? 1 : 2));
}

template<int NW>
__device__ __forceinline__ float breduce_sum(float v, volatile float* red, int t) {
    int w = t >> 6, l = t & 63;
#pragma unroll
    for (int mm = 1; mm < 64; mm <<= 1) v += __shfl_xor(v, mm);
    __syncthreads();
    if (l == 0) red[w] = v;
    __syncthreads();
    float s = red[0];
#pragma unroll
    for (int i = 1; i < NW; i++) s += red[i];
    return s;
}

template<int NW>
__device__ __forceinline__ float breduce_max(float v, volatile float* red, int t) {
    int w = t >> 6, l = t & 63;
#pragma unroll
    for (int mm = 1; mm < 64; mm <<= 1) v = fmaxf(v, __shfl_xor(v, mm));
    __syncthreads();
    if (l == 0) red[w] = v;
    __syncthreads();
    float s = red[0];
#pragma unroll
    for (int i = 1; i < NW; i++) s = fmaxf(s, red[i]);
    return s;
}

// gn[g][b][:] = g / max(||g||, 1e-8)
__global__ __launch_bounds__(64) void k_gnorm(const float* g0, const float* g1, const float* g2,
                                              float* gn) {
    int gm = blockIdx.y, b = blockIdx.x, l = threadIdx.x;
    const float* g = (gm == 0) ? g0 : (gm == 1 ? g1 : g2);
    const float4* gv = (const float4*)(g + (size_t)b * C);
    float4 a = gv[l], bb = gv[64 + l];
    float pp = a.x * a.x + a.y * a.y + a.z * a.z + a.w * a.w +
               bb.x * bb.x + bb.y * bb.y + bb.z * bb.z + bb.w * bb.w;
#pragma unroll
    for (int mm = 1; mm < 64; mm <<= 1) pp += __shfl_xor(pp, mm);
    float inv = 1.0f / fmaxf(sqrtf(pp), 1e-8f);
    float4* o = (float4*)(gn + ((size_t)gm * B + b) * C);
    a.x *= inv; a.y *= inv; a.z *= inv; a.w *= inv;
    bb.x *= inv; bb.y *= inv; bb.z *= inv; bb.w *= inv;
    o[l] = a; o[64 + l] = bb;
}

// part[ks][m][b][c] = sum_{e in slice ks} g_guide[b,e] * qw[m,e,c]
__global__ __launch_bounds__(256) void k_qprojA(const float* g0, const float* g1, const float* g2,
                                                const float* qw, float* part) {
    int cx = blockIdx.x, m = blockIdx.y, ks = blockIdx.z;
    int t = threadIdx.x;
    int c0 = cx * 64, e0 = ks * 64;
    int gi = guide_of(m);
    const float* g = (gi == 0) ? g0 : (gi == 1 ? g1 : g2);
    __shared__ float gt[64][64];  // [b][e]
    for (int idx = t; idx < 1024; idx += 256) {
        int r = idx >> 4, c4 = idx & 15;
        ((float4*)gt[r])[c4] = ((const float4*)(g + (size_t)r * C + e0))[c4];
    }
    __syncthreads();
    int c = c0 + (t & 63);
    int br = (t >> 6) * 16;
    float acc[16];
#pragma unroll
    for (int i = 0; i < 16; i++) acc[i] = 0.f;
    const float* W = qw + (size_t)m * C * C + (size_t)e0 * C + c;
#pragma unroll 4
    for (int e = 0; e < 64; e++) {
        float wv = W[(size_t)e * C];
#pragma unroll
        for (int i = 0; i < 16; i++) acc[i] += gt[br + i][e] * wv;
    }
#pragma unroll
    for (int i = 0; i < 16; i++)
        part[(size_t)ks * 294912 + ((size_t)m * B + br + i) * C + c] = acc[i];
}

// q = sum_ks part + qb  (float4, 288 blocks)
__global__ __launch_bounds__(256) void k_qreduce(const float4* part, const float4* qb, float4* q) {
    int i = blockIdx.x * 256 + threadIdx.x;  // 73728 float4
    float4 s = part[i];
#pragma unroll
    for (int ks = 1; ks < 8; ks++) {
        float4 v = part[(size_t)ks * 73728 + i];
        s.x += v.x; s.y += v.y; s.z += v.z; s.w += v.w;
    }
    int c4 = i & 127;        // C/4 per row
    int m = i >> 13;         // B*C/4 per module
    float4 bv = qb[m * 128 + c4];
    s.x += bv.x; s.y += bv.y; s.z += bv.z; s.w += bv.w;
    q[i] = s;
}

// part[ds][m][b][c] = sum_{d in slice ds} kw[m,c,d] * q[m,b,d]
__global__ __launch_bounds__(256) void k_kprojA(const float* kw, const float* q, float* part) {
    int cx = blockIdx.x, m = blockIdx.y, ds = blockIdx.z;
    int t = threadIdx.x;
    int c0 = cx * 64, d0 = ds * 64;
    __shared__ float kt[64][65];  // [c][d], padded
    __shared__ float qt[64][64];  // [b][d]
    for (int idx = t; idx < 4096; idx += 256) {
        int r = idx >> 6, cc = idx & 63;
        kt[r][cc] = kw[((size_t)m * C + c0 + r) * C + d0 + cc];
        qt[r][cc] = q[((size_t)m * B + r) * C + d0 + cc];
    }
    __syncthreads();
    int c = t & 63;
    int br = (t >> 6) * 16;
    float acc[16];
#pragma unroll
    for (int i = 0; i < 16; i++) acc[i] = 0.f;
#pragma unroll 4
    for (int d = 0; d < 64; d++) {
        float kv = kt[c][d];
#pragma unroll
        for (int i = 0; i < 16; i++) acc[i] += kv * qt[br + i][d];
    }
#pragma unroll
    for (int i = 0; i < 16; i++)
        part[(size_t)ds * 294912 + ((size_t)m * B + br + i) * C + c0 + c] = acc[i];
}

__global__ __launch_bounds__(256) void k_kreduce(const float4* part, float4* qk) {
    int i = blockIdx.x * 256 + threadIdx.x;
    float4 s = part[i];
#pragma unroll
    for (int ks = 1; ks < 8; ks++) {
        float4 v = part[(size_t)ks * 73728 + i];
        s.x += v.x; s.y += v.y; s.z += v.z; s.w += v.w;
    }
    qk[i] = s;
}

// qkb[m][b] = q[m,b,:] . kb[m,:]
__global__ __launch_bounds__(64) void k_qkb(const float* q, const float* kb, float* qkb) {
    int b = blockIdx.x, m = blockIdx.y, l = threadIdx.x;
    const float4* qv = (const float4*)(q + ((size_t)m * B + b) * C);
    const float4* kv = (const float4*)(kb + (size_t)m * C);
    float4 a = qv[l], bb = qv[64 + l];
    float4 c = kv[l], d = kv[64 + l];
    float s = a.x * c.x + a.y * c.y + a.z * c.z + a.w * c.w +
              bb.x * d.x + bb.y * d.y + bb.z * d.z + bb.w * d.w;
#pragma unroll
    for (int mm = 1; mm < 64; mm <<= 1) s += __shfl_xor(s, mm);
    if (l == 0) qkb[m * B + b] = s;
}

// fc1 K-split: h1part[ks][mi][b][col] = sum_{e in slice} gcat[e] * w1[mi][e][col]
__global__ __launch_bounds__(256) void k_mlpA(const float* g0, const float* g1, const float* g2,
                                              const float* w1, float* h1part) {
    int b = blockIdx.x, mi = blockIdx.y, ks = blockIdx.z;  // ks in 0..5, slices of 256
    int t = threadIdx.x;
    __shared__ float gcs[256];
    const float* g = (ks < 2) ? g0 : (ks < 4 ? g1 : g2);
    gcs[t] = g[(size_t)b * C + (ks & 1) * 256 + t];
    __syncthreads();
    float acc = 0.f;
    const float* W1 = w1 + ((size_t)mi * 1536 + ks * 256) * 256 + t;
#pragma unroll 8
    for (int e = 0; e < 256; e++) acc += gcs[e] * W1[(size_t)e * 256];
    h1part[(((size_t)ks * 3 + mi) * B + b) * 256 + t] = acc;
}

// reduce + LN + gelu + fc2 + gelu + fc3 + softmax -> wmix
__global__ __launch_bounds__(256) void k_mlpB(const float* h1part,
                                              const float* b1, const float* lng, const float* lnb,
                                              const float* w2, const float* b2,
                                              const float* w3, const float* b3, float* wmix) {
    int b = blockIdx.x, mi = blockIdx.y, t = threadIdx.x;
    __shared__ float h1[256];
    __shared__ float h2p[4][64];
    __shared__ float h2[64];
    __shared__ float red[4];
    float a1 = b1[mi * 256 + t];
#pragma unroll
    for (int ks = 0; ks < 6; ks++) a1 += h1part[(((size_t)ks * 3 + mi) * B + b) * 256 + t];
    float total = breduce_sum<4>(a1, red, t);
    float mean = total * (1.0f / 256.0f);
    float dv = a1 - mean;
    float vtot = breduce_sum<4>(dv * dv, red, t);
    float var = vtot * (1.0f / 256.0f);
    float x = dv / sqrtf(var + 1e-5f) * lng[mi * 256 + t] + lnb[mi * 256 + t];
    x = 0.5f * x * (1.0f + erff(x * 0.70710678118654752f));
    h1[t] = x;
    __syncthreads();
    {
        int col = t & 63, sl = t >> 6;  // 4 slices of 64
        float a2 = 0.f;
        const float* W2 = w2 + (size_t)mi * 256 * 64 + col;
#pragma unroll 8
        for (int e = sl * 64; e < sl * 64 + 64; e++) a2 += h1[e] * W2[(size_t)e * 64];
        h2p[sl][col] = a2;
    }
    __syncthreads();
    if (t < 64) {
        float a2 = b2[mi * 64 + t];
#pragma unroll
        for (int s2 = 0; s2 < 4; s2++) a2 += h2p[s2][t];
        a2 = 0.5f * a2 * (1.0f + erff(a2 * 0.70710678118654752f));
        h2[t] = a2;
    }
    __syncthreads();
    if (t == 0) {
        float l3[3];
        for (int j = 0; j < 3; j++) {
            float a3 = b3[mi * 3 + j];
            for (int e = 0; e < 64; e++) a3 += h2[e] * w3[((size_t)mi * 64 + e) * 3 + j];
            l3[j] = a3;
        }
        float mx = fmaxf(l3[0], fmaxf(l3[1], l3[2]));
        float e0 = expf(l3[0] - mx), e1 = expf(l3[1] - mx), e2 = expf(l3[2] - mx);
        float inv = 1.0f / (e0 + e1 + e2);
        wmix[((size_t)mi * B + b) * 4 + 0] = e0 * inv;
        wmix[((size_t)mi * B + b) * 4 + 1] = e1 * inv;
        wmix[((size_t)mi * B + b) * 4 + 2] = e2 * inv;
    }
}

__device__ __forceinline__ float dot4(float4 a, float4 b) {
    return a.x * b.x + a.y * b.y + a.z * b.z + a.w * b.w;
}

// logits: grid (B, 3, 8) x 256 threads; each block does 32 tokens
__global__ __launch_bounds__(256) void k_logits(const float* p0, const float* p1, const float* p2,
                                                const float* qk, const float* qkb, const float* gn,
                                                float* lgt) {
    int b = blockIdx.x, mi = blockIdx.y, ns = blockIdx.z;
    int t = threadIdx.x, w = t >> 6, l = t & 63;
    const float* p = (mi == 0) ? p0 : (mi == 1 ? p1 : p2);
    float4 qa[3], qb_[3], ga[3], gb_[3];
    float qkbv[3];
#pragma unroll
    for (int j = 0; j < 3; j++) {
        int m = 3 * mi + j;
        int gi = guide_of(m);
        const float4* qv = (const float4*)(qk + ((size_t)m * B + b) * C);
        qa[j] = qv[l]; qb_[j] = qv[64 + l];
        const float4* gv = (const float4*)(gn + ((size_t)gi * B + b) * C);
        ga[j] = gv[l]; gb_[j] = gv[64 + l];
        qkbv[j] = qkb[m * B + b];
    }
    const float4* pbase = (const float4*)(p + (size_t)b * N * C);
    const float SCALE = 0.044194173824159216f;  // 512^-0.5
    float* L = lgt + ((size_t)(mi * B + b) * 3) * N;
    int n0 = ns * 32;
#pragma unroll
    for (int i = 0; i < 8; i++) {
        int n = n0 + w + 4 * i;  // waves interleave over consecutive tokens
        float4 pa = pbase[(size_t)n * 128 + l];
        float4 pb = pbase[(size_t)n * 128 + 64 + l];
        float pp = dot4(pa, pa) + dot4(pb, pb);
        float dj[3], cj[3];
#pragma unroll
        for (int j = 0; j < 3; j++) {
            dj[j] = dot4(pa, qa[j]) + dot4(pb, qb_[j]);
            cj[j] = dot4(pa, ga[j]) + dot4(pb, gb_[j]);
        }
#pragma unroll
        for (int mm = 1; mm < 64; mm <<= 1) {
            pp += __shfl_xor(pp, mm);
#pragma unroll
            for (int j = 0; j < 3; j++) {
                dj[j] += __shfl_xor(dj[j], mm);
                cj[j] += __shfl_xor(cj[j], mm);
            }
        }
        if (l == 0) {
            float rn = fmaxf(sqrtf(pp), 1e-8f);
#pragma unroll
            for (int j = 0; j < 3; j++)
                L[j * N + n] = (dj[j] + qkbv[j]) * SCALE + (cj[j] / rn) * (1.0f / 0.3f);
        }
    }
}

// finish: per (mi,b): softmax -> zscore+sigmoid -> mix -> quantile -> mask
__global__ __launch_bounds__(256) void k_finish(const float* lgt, const float* wmix,
                                                float* msk, float* out) {
    int b = blockIdx.x, mi = blockIdx.y, t = threadIdx.x;
    __shared__ float sc[256];
    __shared__ float red[4];
    __shared__ float thr_s;
    const float* L = lgt + ((size_t)(mi * B + b) * 3) * N;
    float wj[3];
#pragma unroll
    for (int j = 0; j < 3; j++) wj[j] = wmix[((size_t)mi * B + b) * 4 + j];
    float score = 0.f;
    for (int j = 0; j < 3; j++) {
        float v = L[j * N + t];
        float mx = breduce_max<4>(v, red, t);
        float e = expf(v - mx);
        float s = breduce_sum<4>(e, red, t);
        float pr = e / s;
        float total = breduce_sum<4>(pr, red, t);
        float mean = total * (1.0f / 256.0f);
        float dv = pr - mean;
        float vtot = breduce_sum<4>(dv * dv, red, t);
        float sd = sqrtf(vtot * (1.0f / 255.0f)) + 1e-5f;
        float z = dv / sd;
        float sg = 1.0f / (1.0f + expf(-z));
        score += wj[j] * sg;
    }
    sc[t] = score;
    __syncthreads();
    {
        int cl = 0, ce = 0;
        for (int m2 = 0; m2 < N; m2++) {
            float v2 = sc[m2];
            cl += (v2 < score) ? 1 : 0;
            ce += (v2 == score) ? 1 : 0;
        }
        if (cl <= 102 && 102 < cl + ce) thr_s = score;
    }
    __syncthreads();
    float thr = thr_s;
    float mk = 1.0f / (1.0f + expf(-(score - thr) * (1.0f / 0.3f)));
    msk[((size_t)mi * B + b) * N + t] = mk;
    out[(size_t)3 * B * N * C + ((size_t)mi * B + b) * N + t] = mk;
}

// scale: elementwise tokens * mask, grid-stride float4
__global__ __launch_bounds__(256) void k_scale(const float* p0, const float* p1, const float* p2,
                                               const float* msk, float4* out) {
    const int TOT = 3 * B * N * C / 4;  // 6291456
    const float4* pb[3] = {(const float4*)p0, (const float4*)p1, (const float4*)p2};
    for (int idx = blockIdx.x * 256 + threadIdx.x; idx < TOT; idx += gridDim.x * 256) {
        int mi = idx >> 21;                 // B*N*C/4 = 2^21 per modality
        int r = idx & ((1 << 21) - 1);
        float4 v = pb[mi][r];
        float mkv = msk[(mi << 14) + (r >> 7)];  // 128 float4 per token, B*N=2^14
        v.x *= mkv; v.y *= mkv; v.z *= mkv; v.w *= mkv;
        out[idx] = v;
    }
}

extern "C" void kernel_launch(void* const* d_in, const int* in_sizes, int n_in,
                              void* d_out, int out_size, void* d_ws, size_t ws_size,
                              hipStream_t stream) {
    const float* rgb   = (const float*)d_in[0];
    const float* nir   = (const float*)d_in[1];
    const float* tir   = (const float*)d_in[2];
    const float* rgb_g = (const float*)d_in[3];
    const float* nir_g = (const float*)d_in[4];
    const float* tir_g = (const float*)d_in[5];
    const float* attn_qw = (const float*)d_in[6];
    const float* attn_qb = (const float*)d_in[7];
    const float* attn_kw = (const float*)d_in[8];
    const float* attn_kb = (const float*)d_in[9];
    const float* mlp_w1 = (const float*)d_in[10];
    const float* mlp_b1 = (const float*)d_in[11];
    const float* ln_g = (const float*)d_in[12];
    const float* ln_b = (const float*)d_in[13];
    const float* mlp_w2 = (const float*)d_in[14];
    const float* mlp_b2 = (const float*)d_in[15];
    const float* mlp_w3 = (const float*)d_in[16];
    const float* mlp_b3 = (const float*)d_in[17];
    float* out = (float*)d_out;

    float* ws = (float*)d_ws;
    // layout (floats):
    float* part   = ws;                  // 8*294912 = 2359296
    float* q      = ws + 2359296;        // 294912
    float* qk     = ws + 2654208;        // 294912
    float* qkb    = ws + 2949120;        // 576 -> pad 1024
    float* gn     = ws + 2950144;        // 98304
    float* wmix   = ws + 3048448;        // 768
    float* h1part = ws + 3049216;        // 6*3*64*256 = 294912
    float* lgt    = ws + 3344128;        // 3*64*3*256 = 147456
    float* msk    = ws + 3491584;        // 3*64*256 = 49152
    // total 3540736 floats = 14.2 MB

    k_gnorm<<<dim3(B, 3), 64, 0, stream>>>(rgb_g, nir_g, tir_g, gn);
    k_qprojA<<<dim3(8, 9, 8), 256, 0, stream>>>(rgb_g, nir_g, tir_g, attn_qw, part);
    k_qreduce<<<288, 256, 0, stream>>>((const float4*)part, (const float4*)attn_qb, (float4*)q);
    k_kprojA<<<dim3(8, 9, 8), 256, 0, stream>>>(attn_kw, q, part);
    k_kreduce<<<288, 256, 0, stream>>>((const float4*)part, (float4*)qk);
    k_qkb<<<dim3(B, 9), 64, 0, stream>>>(q, attn_kb, qkb);
    k_mlpA<<<dim3(B, 3, 6), 256, 0, stream>>>(rgb_g, nir_g, tir_g, mlp_w1, h1part);
    k_mlpB<<<dim3(B, 3), 256, 0, stream>>>(h1part, mlp_b1, ln_g, ln_b,
                                           mlp_w2, mlp_b2, mlp_w3, mlp_b3, wmix);
    k_logits<<<dim3(B, 3, 8), 256, 0, stream>>>(rgb, nir, tir, qk, qkb, gn, lgt);
    k_finish<<<dim3(B, 3), 256, 0, stream>>>(lgt, wmix, msk, out);
    k_scale<<<2048, 256, 0, stream>>>(rgb, nir, tir, msk, (float4*)out);
}

// Round 4
// 131.882 us; speedup vs baseline: 2.8934x; 1.0657x over previous
//
#include <hip/hip_runtime.h>
#include <math.h>

#define B 64
#define N 256
#define C 512

// guide modality for module m = 3*mi + j
__device__ __forceinline__ int guide_of(int m) {
    int mi = m / 3, j = m % 3;
    return (j == 0) ? mi : (j == 1 ? ((mi == 0) ? 1 : 0) : ((mi == 2) ? 1 : 2));
}

template<int NW>
__device__ __forceinline__ float breduce_sum(float v, volatile float* red, int t) {
    int w = t >> 6, l = t & 63;
#pragma unroll
    for (int mm = 1; mm < 64; mm <<= 1) v += __shfl_xor(v, mm);
    __syncthreads();
    if (l == 0) red[w] = v;
    __syncthreads();
    float s = red[0];
#pragma unroll
    for (int i = 1; i < NW; i++) s += red[i];
    return s;
}

template<int NW>
__device__ __forceinline__ float breduce_max(float v, volatile float* red, int t) {
    int w = t >> 6, l = t & 63;
#pragma unroll
    for (int mm = 1; mm < 64; mm <<= 1) v = fmaxf(v, __shfl_xor(v, mm));
    __syncthreads();
    if (l == 0) red[w] = v;
    __syncthreads();
    float s = red[0];
#pragma unroll
    for (int i = 1; i < NW; i++) s = fmaxf(s, red[i]);
    return s;
}

// part[ks][m][b][c] = sum_{e in slice ks} g_guide[b,e] * qw[m,e,c]
__global__ __launch_bounds__(256) void k_qprojA(const float* g0, const float* g1, const float* g2,
                                                const float* qw, float* part) {
    int cx = blockIdx.x, m = blockIdx.y, ks = blockIdx.z;
    int t = threadIdx.x;
    int c0 = cx * 64, e0 = ks * 64;
    int gi = guide_of(m);
    const float* g = (gi == 0) ? g0 : (gi == 1 ? g1 : g2);
    __shared__ float gt[64][64];  // [b][e]
    for (int idx = t; idx < 1024; idx += 256) {
        int r = idx >> 4, c4 = idx & 15;
        ((float4*)gt[r])[c4] = ((const float4*)(g + (size_t)r * C + e0))[c4];
    }
    __syncthreads();
    int c = c0 + (t & 63);
    int br = (t >> 6) * 16;
    float acc[16];
#pragma unroll
    for (int i = 0; i < 16; i++) acc[i] = 0.f;
    const float* W = qw + (size_t)m * C * C + (size_t)e0 * C + c;
#pragma unroll 4
    for (int e = 0; e < 64; e++) {
        float wv = W[(size_t)e * C];
#pragma unroll
        for (int i = 0; i < 16; i++) acc[i] += gt[br + i][e] * wv;
    }
#pragma unroll
    for (int i = 0; i < 16; i++)
        part[(size_t)ks * 294912 + ((size_t)m * B + br + i) * C + c] = acc[i];
}

// q = sum_ks part + qb ; qkb[row] = q[row,:].kb[m,:]  (288 blocks, 2 rows/block)
__global__ __launch_bounds__(256) void k_qreduce(const float4* part, const float4* qb4,
                                                 const float4* kb4, float4* q, float* qkb) {
    int t = threadIdx.x;
    int i = blockIdx.x * 256 + t;  // 73728 float4
    float4 s = part[i];
#pragma unroll
    for (int ks = 1; ks < 8; ks++) {
        float4 v = part[(size_t)ks * 73728 + i];
        s.x += v.x; s.y += v.y; s.z += v.z; s.w += v.w;
    }
    int c4 = i & 127;        // C/4 per row
    int row = i >> 7;        // m*64 + b, 0..575
    int m = row >> 6;
    float4 bv = qb4[m * 128 + c4];
    s.x += bv.x; s.y += bv.y; s.z += bv.z; s.w += bv.w;
    q[i] = s;
    // fused qkb: dot row with kb
    float4 kv = kb4[m * 128 + c4];
    float p = s.x * kv.x + s.y * kv.y + s.z * kv.z + s.w * kv.w;
#pragma unroll
    for (int mm = 1; mm < 64; mm <<= 1) p += __shfl_xor(p, mm);
    __shared__ float red[4];
    int w = t >> 6;
    if ((t & 63) == 0) red[w] = p;
    __syncthreads();
    if ((t & 127) == 0) qkb[row] = red[w] + red[w + 1];
}

// part[ds][m][b][c] = sum_{d in slice ds} kw[m,c,d] * q[m,b,d]
__global__ __launch_bounds__(256) void k_kprojA(const float* kw, const float* q, float* part) {
    int cx = blockIdx.x, m = blockIdx.y, ds = blockIdx.z;
    int t = threadIdx.x;
    int c0 = cx * 64, d0 = ds * 64;
    __shared__ float kt[64][65];  // [c][d], padded (stride 65 -> conflict-free reads)
    __shared__ float qt[64][64];  // [b][d]
    for (int idx = t; idx < 1024; idx += 256) {
        int r = idx >> 4, c4 = idx & 15;
        float4 kv4 = *(const float4*)(kw + ((size_t)m * C + c0 + r) * C + d0 + c4 * 4);
        kt[r][c4 * 4 + 0] = kv4.x; kt[r][c4 * 4 + 1] = kv4.y;
        kt[r][c4 * 4 + 2] = kv4.z; kt[r][c4 * 4 + 3] = kv4.w;
        ((float4*)qt[r])[c4] = *(const float4*)(q + ((size_t)m * B + r) * C + d0 + c4 * 4);
    }
    __syncthreads();
    int c = t & 63;
    int br = (t >> 6) * 16;
    float acc[16];
#pragma unroll
    for (int i = 0; i < 16; i++) acc[i] = 0.f;
#pragma unroll 4
    for (int d = 0; d < 64; d++) {
        float kv = kt[c][d];
#pragma unroll
        for (int i = 0; i < 16; i++) acc[i] += kv * qt[br + i][d];
    }
#pragma unroll
    for (int i = 0; i < 16; i++)
        part[(size_t)ds * 294912 + ((size_t)m * B + br + i) * C + c0 + c] = acc[i];
}

__global__ __launch_bounds__(256) void k_kreduce(const float4* part, float4* qk) {
    int i = blockIdx.x * 256 + threadIdx.x;
    float4 s = part[i];
#pragma unroll
    for (int ks = 1; ks < 8; ks++) {
        float4 v = part[(size_t)ks * 73728 + i];
        s.x += v.x; s.y += v.y; s.z += v.z; s.w += v.w;
    }
    qk[i] = s;
}

// fc1 as tiled GEMM: grid (cx=4, mi=3, ks=12); 64 b x 64 cols per block, K-slice 128.
// Every w1 element read exactly once.
__global__ __launch_bounds__(256) void k_mlpA(const float* g0, const float* g1, const float* g2,
                                              const float* w1, float* h1part) {
    int cx = blockIdx.x, mi = blockIdx.y, ks = blockIdx.z;
    int t = threadIdx.x;
    int e0 = ks * 128;  // within 1536
    const float* g = (e0 < 512) ? g0 : (e0 < 1024 ? g1 : g2);
    int eo = e0 & 511;
    __shared__ float gt[64][128];
    for (int idx = t; idx < 2048; idx += 256) {
        int r = idx >> 5, c4 = idx & 31;
        ((float4*)gt[r])[c4] = *(const float4*)(g + (size_t)r * C + eo + c4 * 4);
    }
    __syncthreads();
    int c = cx * 64 + (t & 63);
    int br = (t >> 6) * 16;
    float acc[16];
#pragma unroll
    for (int i = 0; i < 16; i++) acc[i] = 0.f;
    const float* W = w1 + ((size_t)mi * 1536 + e0) * 256 + c;
#pragma unroll 4
    for (int e = 0; e < 128; e++) {
        float wv = W[(size_t)e * 256];
#pragma unroll
        for (int i = 0; i < 16; i++) acc[i] += gt[br + i][e] * wv;
    }
#pragma unroll
    for (int i = 0; i < 16; i++)
        h1part[(((size_t)ks * 3 + mi) * B + br + i) * 256 + c] = acc[i];
}

__device__ __forceinline__ float dot4(float4 a, float4 b) {
    return a.x * b.x + a.y * b.y + a.z * b.z + a.w * b.w;
}

// logits: grid (B, 3, 8) x 256 threads; 32 tokens/block; g-norm computed inline
__global__ __launch_bounds__(256) void k_logits(const float* p0, const float* p1, const float* p2,
                                                const float* qk, const float* qkb,
                                                const float* g0, const float* g1, const float* g2,
                                                float* lgt) {
    int b = blockIdx.x, mi = blockIdx.y, ns = blockIdx.z;
    int t = threadIdx.x, w = t >> 6, l = t & 63;
    const float* p = (mi == 0) ? p0 : (mi == 1 ? p1 : p2);
    float4 qa[3], qb_[3], ga[3], gb_[3];
    float qkbv[3];
#pragma unroll
    for (int j = 0; j < 3; j++) {
        int m = 3 * mi + j;
        int gi = guide_of(m);
        const float4* qv = (const float4*)(qk + ((size_t)m * B + b) * C);
        qa[j] = qv[l]; qb_[j] = qv[64 + l];
        const float* graw = (gi == 0) ? g0 : (gi == 1 ? g1 : g2);
        const float4* gv = (const float4*)(graw + (size_t)b * C);
        ga[j] = gv[l]; gb_[j] = gv[64 + l];
        float n2 = dot4(ga[j], ga[j]) + dot4(gb_[j], gb_[j]);
#pragma unroll
        for (int mm = 1; mm < 64; mm <<= 1) n2 += __shfl_xor(n2, mm);
        float ginv = 1.0f / fmaxf(sqrtf(n2), 1e-8f);
        ga[j].x *= ginv; ga[j].y *= ginv; ga[j].z *= ginv; ga[j].w *= ginv;
        gb_[j].x *= ginv; gb_[j].y *= ginv; gb_[j].z *= ginv; gb_[j].w *= ginv;
        qkbv[j] = qkb[m * B + b];
    }
    const float4* pbase = (const float4*)(p + (size_t)b * N * C);
    const float SCALE = 0.044194173824159216f;  // 512^-0.5
    float* L = lgt + ((size_t)(mi * B + b) * 3) * N;
    int n0 = ns * 32;
#pragma unroll
    for (int i = 0; i < 8; i++) {
        int n = n0 + w + 4 * i;
        float4 pa = pbase[(size_t)n * 128 + l];
        float4 pb = pbase[(size_t)n * 128 + 64 + l];
        float pp = dot4(pa, pa) + dot4(pb, pb);
        float dj[3], cj[3];
#pragma unroll
        for (int j = 0; j < 3; j++) {
            dj[j] = dot4(pa, qa[j]) + dot4(pb, qb_[j]);
            cj[j] = dot4(pa, ga[j]) + dot4(pb, gb_[j]);
        }
#pragma unroll
        for (int mm = 1; mm < 64; mm <<= 1) {
            pp += __shfl_xor(pp, mm);
#pragma unroll
            for (int j = 0; j < 3; j++) {
                dj[j] += __shfl_xor(dj[j], mm);
                cj[j] += __shfl_xor(cj[j], mm);
            }
        }
        if (l == 0) {
            float rn = fmaxf(sqrtf(pp), 1e-8f);
#pragma unroll
            for (int j = 0; j < 3; j++)
                L[j * N + n] = (dj[j] + qkbv[j]) * SCALE + (cj[j] / rn) * (1.0f / 0.3f);
        }
    }
}

// finish (fused adaptive-weight MLP + score): per (mi,b)
__global__ __launch_bounds__(256) void k_finish(const float* lgt, const float* h1part,
                                                const float* b1, const float* lng, const float* lnb,
                                                const float* w2, const float* b2,
                                                const float* w3, const float* b3,
                                                const float* wmix_unused,
                                                float* msk, float* out) {
    int b = blockIdx.x, mi = blockIdx.y, t = threadIdx.x;
    __shared__ float h1[256];
    __shared__ float h2p[4][64];
    __shared__ float h2[64];
    __shared__ float red[4];
    __shared__ float wjs[3];
    __shared__ float sc[256];
    __shared__ float thr_s;
    // --- MLP phase ---
    float a1 = b1[mi * 256 + t];
#pragma unroll
    for (int ks = 0; ks < 12; ks++) a1 += h1part[(((size_t)ks * 3 + mi) * B + b) * 256 + t];
    float total = breduce_sum<4>(a1, red, t);
    float mean = total * (1.0f / 256.0f);
    float dv = a1 - mean;
    float vtot = breduce_sum<4>(dv * dv, red, t);
    float var = vtot * (1.0f / 256.0f);
    float x = dv / sqrtf(var + 1e-5f) * lng[mi * 256 + t] + lnb[mi * 256 + t];
    x = 0.5f * x * (1.0f + erff(x * 0.70710678118654752f));
    h1[t] = x;
    __syncthreads();
    {
        int col = t & 63, sl = t >> 6;  // 4 slices of 64
        float a2 = 0.f;
        const float* W2 = w2 + (size_t)mi * 256 * 64 + col;
#pragma unroll 8
        for (int e = sl * 64; e < sl * 64 + 64; e++) a2 += h1[e] * W2[(size_t)e * 64];
        h2p[sl][col] = a2;
    }
    __syncthreads();
    if (t < 64) {
        float a2 = b2[mi * 64 + t];
#pragma unroll
        for (int s2 = 0; s2 < 4; s2++) a2 += h2p[s2][t];
        a2 = 0.5f * a2 * (1.0f + erff(a2 * 0.70710678118654752f));
        h2[t] = a2;
    }
    __syncthreads();
    if (t == 0) {
        float l3[3];
        for (int j = 0; j < 3; j++) {
            float a3 = b3[mi * 3 + j];
            for (int e = 0; e < 64; e++) a3 += h2[e] * w3[((size_t)mi * 64 + e) * 3 + j];
            l3[j] = a3;
        }
        float mx = fmaxf(l3[0], fmaxf(l3[1], l3[2]));
        float e0 = expf(l3[0] - mx), e1 = expf(l3[1] - mx), e2 = expf(l3[2] - mx);
        float inv = 1.0f / (e0 + e1 + e2);
        wjs[0] = e0 * inv; wjs[1] = e1 * inv; wjs[2] = e2 * inv;
    }
    __syncthreads();
    // --- score phase ---
    const float* L = lgt + ((size_t)(mi * B + b) * 3) * N;
    float score = 0.f;
    for (int j = 0; j < 3; j++) {
        float v = L[j * N + t];
        float mx = breduce_max<4>(v, red, t);
        float e = expf(v - mx);
        float s = breduce_sum<4>(e, red, t);
        float pr = e / s;
        float tot2 = breduce_sum<4>(pr, red, t);
        float mean2 = tot2 * (1.0f / 256.0f);
        float dv2 = pr - mean2;
        float vtot2 = breduce_sum<4>(dv2 * dv2, red, t);
        float sd = sqrtf(vtot2 * (1.0f / 255.0f)) + 1e-5f;
        float z = dv2 / sd;
        float sg = 1.0f / (1.0f + expf(-z));
        score += wjs[j] * sg;
    }
    sc[t] = score;
    __syncthreads();
    {
        int cl = 0, ce = 0;
        for (int m2 = 0; m2 < N; m2++) {
            float v2 = sc[m2];
            cl += (v2 < score) ? 1 : 0;
            ce += (v2 == score) ? 1 : 0;
        }
        if (cl <= 102 && 102 < cl + ce) thr_s = score;
    }
    __syncthreads();
    float thr = thr_s;
    float mk = 1.0f / (1.0f + expf(-(score - thr) * (1.0f / 0.3f)));
    msk[((size_t)mi * B + b) * N + t] = mk;
    out[(size_t)3 * B * N * C + ((size_t)mi * B + b) * N + t] = mk;
}

// scale: elementwise tokens * mask, grid-stride float4
__global__ __launch_bounds__(256) void k_scale(const float* p0, const float* p1, const float* p2,
                                               const float* msk, float4* out) {
    const int TOT = 3 * B * N * C / 4;  // 6291456
    const float4* pb[3] = {(const float4*)p0, (const float4*)p1, (const float4*)p2};
    for (int idx = blockIdx.x * 256 + threadIdx.x; idx < TOT; idx += gridDim.x * 256) {
        int mi = idx >> 21;                 // B*N*C/4 = 2^21 per modality
        int r = idx & ((1 << 21) - 1);
        float4 v = pb[mi][r];
        float mkv = msk[(mi << 14) + (r >> 7)];  // 128 float4 per token
        v.x *= mkv; v.y *= mkv; v.z *= mkv; v.w *= mkv;
        out[idx] = v;
    }
}

extern "C" void kernel_launch(void* const* d_in, const int* in_sizes, int n_in,
                              void* d_out, int out_size, void* d_ws, size_t ws_size,
                              hipStream_t stream) {
    const float* rgb   = (const float*)d_in[0];
    const float* nir   = (const float*)d_in[1];
    const float* tir   = (const float*)d_in[2];
    const float* rgb_g = (const float*)d_in[3];
    const float* nir_g = (const float*)d_in[4];
    const float* tir_g = (const float*)d_in[5];
    const float* attn_qw = (const float*)d_in[6];
    const float* attn_qb = (const float*)d_in[7];
    const float* attn_kw = (const float*)d_in[8];
    const float* attn_kb = (const float*)d_in[9];
    const float* mlp_w1 = (const float*)d_in[10];
    const float* mlp_b1 = (const float*)d_in[11];
    const float* ln_g = (const float*)d_in[12];
    const float* ln_b = (const float*)d_in[13];
    const float* mlp_w2 = (const float*)d_in[14];
    const float* mlp_b2 = (const float*)d_in[15];
    const float* mlp_w3 = (const float*)d_in[16];
    const float* mlp_b3 = (const float*)d_in[17];
    float* out = (float*)d_out;

    float* ws = (float*)d_ws;
    // layout (floats):
    float* part   = ws;                  // 8*294912 = 2359296
    float* q      = ws + 2359296;        // 294912
    float* qk     = ws + 2654208;        // 294912
    float* qkb    = ws + 2949120;        // 576 -> pad 1024
    float* h1part = ws + 2950144;        // 12*3*64*256 = 589824
    float* lgt    = ws + 3539968;        // 3*64*3*256 = 147456
    float* msk    = ws + 3687424;        // 49152
    // total 3736576 floats = 15.0 MB

    k_qprojA<<<dim3(8, 9, 8), 256, 0, stream>>>(rgb_g, nir_g, tir_g, attn_qw, part);
    k_qreduce<<<288, 256, 0, stream>>>((const float4*)part, (const float4*)attn_qb,
                                       (const float4*)attn_kb, (float4*)q, qkb);
    k_kprojA<<<dim3(8, 9, 8), 256, 0, stream>>>(attn_kw, q, part);
    k_kreduce<<<288, 256, 0, stream>>>((const float4*)part, (float4*)qk);
    k_mlpA<<<dim3(4, 3, 12), 256, 0, stream>>>(rgb_g, nir_g, tir_g, mlp_w1, h1part);
    k_logits<<<dim3(B, 3, 8), 256, 0, stream>>>(rgb, nir, tir, qk, qkb,
                                                rgb_g, nir_g, tir_g, lgt);
    k_finish<<<dim3(B, 3), 256, 0, stream>>>(lgt, h1part, mlp_b1, ln_g, ln_b,
                                             mlp_w2, mlp_b2, mlp_w3, mlp_b3, nullptr, msk, out);
    k_scale<<<2048, 256, 0, stream>>>(rgb, nir, tir, msk, (float4*)out);
}

// Round 6
// 120.664 us; speedup vs baseline: 3.1625x; 1.0930x over previous
//
#include <hip/hip_runtime.h>
#include <math.h>

#define B 64
#define N 256
#define C 512

typedef float nfloat4 __attribute__((ext_vector_type(4)));

// guide modality for module m = 3*mi + j
__device__ __forceinline__ int guide_of(int m) {
    int mi = m / 3, j = m % 3;
    return (j == 0) ? mi : (j == 1 ? ((mi == 0) ? 1 : 0) : ((mi == 2) ? 1 : 2));
}

template<int NW>
__device__ __forceinline__ float breduce_sum(float v, volatile float* red, int t) {
    int w = t >> 6, l = t & 63;
#pragma unroll
    for (int mm = 1; mm < 64; mm <<= 1) v += __shfl_xor(v, mm);
    __syncthreads();
    if (l == 0) red[w] = v;
    __syncthreads();
    float s = red[0];
#pragma unroll
    for (int i = 1; i < NW; i++) s += red[i];
    return s;
}

template<int NW>
__device__ __forceinline__ float breduce_max(float v, volatile float* red, int t) {
    int w = t >> 6, l = t & 63;
#pragma unroll
    for (int mm = 1; mm < 64; mm <<= 1) v = fmaxf(v, __shfl_xor(v, mm));
    __syncthreads();
    if (l == 0) red[w] = v;
    __syncthreads();
    float s = red[0];
#pragma unroll
    for (int i = 1; i < NW; i++) s = fmaxf(s, red[i]);
    return s;
}

__device__ __forceinline__ float dot4(float4 a, float4 b) {
    return a.x * b.x + a.y * b.y + a.z * b.z + a.w * b.w;
}

// Fused: qproj partials (blocks 0..575) + mlp fc1 tiles (blocks 576..719)
// qproj: part[ks][m][b][c] = sum_{e in slice ks} g_guide[b,e] * qw[m,e,c]
// mlp:   h1part[ks2][mi][b][col] = sum_{e in 128-slice ks2} gcat[b,e] * w1[mi][e][col]
__global__ __launch_bounds__(256) void k_proj_mlp(const float* g0, const float* g1, const float* g2,
                                                  const float* qw, const float* w1,
                                                  float* part, float* h1part) {
    int bid = blockIdx.x;
    int t = threadIdx.x;
    __shared__ float gt[64 * 128];
    if (bid < 576) {
        int cx = bid & 7, m = (bid >> 3) % 9, ks = bid / 72;
        int c0 = cx * 64, e0 = ks * 64;
        int gi = guide_of(m);
        const float* g = (gi == 0) ? g0 : (gi == 1 ? g1 : g2);
        for (int idx = t; idx < 1024; idx += 256) {
            int r = idx >> 4, c4 = idx & 15;
            ((float4*)&gt[r * 128])[c4] = ((const float4*)(g + (size_t)r * C + e0))[c4];
        }
        __syncthreads();
        int c = c0 + (t & 63);
        int br = (t >> 6) * 16;
        float acc[16];
#pragma unroll
        for (int i = 0; i < 16; i++) acc[i] = 0.f;
        const float* W = qw + (size_t)m * C * C + (size_t)e0 * C + c;
#pragma unroll 4
        for (int e = 0; e < 64; e++) {
            float wv = W[(size_t)e * C];
#pragma unroll
            for (int i = 0; i < 16; i++) acc[i] += gt[(br + i) * 128 + e] * wv;
        }
#pragma unroll
        for (int i = 0; i < 16; i++)
            part[(size_t)ks * 294912 + ((size_t)m * B + br + i) * C + c] = acc[i];
    } else {
        int r = bid - 576;  // 0..143 : (cx=4, mi=3, ks=12)
        int cx = r & 3, mi = (r >> 2) % 3, ks = r / 12;
        int e0 = ks * 128;
        const float* g = (e0 < 512) ? g0 : (e0 < 1024 ? g1 : g2);
        int eo = e0 & 511;
        for (int idx = t; idx < 2048; idx += 256) {
            int rr = idx >> 5, c4 = idx & 31;
            ((float4*)&gt[rr * 128])[c4] = ((const float4*)(g + (size_t)rr * C + eo))[c4];
        }
        __syncthreads();
        int c = cx * 64 + (t & 63);
        int br = (t >> 6) * 16;
        float acc[16];
#pragma unroll
        for (int i = 0; i < 16; i++) acc[i] = 0.f;
        const float* W = w1 + ((size_t)mi * 1536 + e0) * 256 + c;
#pragma unroll 4
        for (int e = 0; e < 128; e++) {
            float wv = W[(size_t)e * 256];
#pragma unroll
            for (int i = 0; i < 16; i++) acc[i] += gt[(br + i) * 128 + e] * wv;
        }
#pragma unroll
        for (int i = 0; i < 16; i++)
            h1part[(((size_t)ks * 3 + mi) * B + br + i) * 256 + c] = acc[i];
    }
}

// kpart[ds][m][b][c] = sum_{d in slice ds} kw[m,c,d] * q[m,b,d]
// with q inline-reduced: q[m,b,d] = sum_ks part[ks][m][b][d] + qb[m,d]
// qkb_part[m][ds][b] = sum_{d in slice} q[m,b,d]*kb[m,d]  (cx==0 blocks only)
__global__ __launch_bounds__(256) void k_kproj(const float* kw, const float* part,
                                               const float* qb, const float* kb,
                                               float* kpart, float* qkb_part) {
    int cx = blockIdx.x, m = blockIdx.y, ds = blockIdx.z;
    int t = threadIdx.x;
    int c0 = cx * 64, d0 = ds * 64;
    __shared__ float kt[64][65];  // [c][d], padded
    __shared__ float qt[64][64];  // [b][d]
    for (int idx = t; idx < 1024; idx += 256) {
        int r = idx >> 4, c4 = idx & 15;
        float4 kv4 = *(const float4*)(kw + ((size_t)m * C + c0 + r) * C + d0 + c4 * 4);
        kt[r][c4 * 4 + 0] = kv4.x; kt[r][c4 * 4 + 1] = kv4.y;
        kt[r][c4 * 4 + 2] = kv4.z; kt[r][c4 * 4 + 3] = kv4.w;
        float4 s = *(const float4*)(qb + (size_t)m * C + d0 + c4 * 4);
        const float* pp = part + ((size_t)m * B + r) * C + d0 + c4 * 4;
#pragma unroll
        for (int ks = 0; ks < 8; ks++) {
            float4 v = *(const float4*)(pp + (size_t)ks * 294912);
            s.x += v.x; s.y += v.y; s.z += v.z; s.w += v.w;
        }
        ((float4*)qt[r])[c4] = s;
    }
    __syncthreads();
    int c = t & 63;
    int br = (t >> 6) * 16;
    float acc[16];
#pragma unroll
    for (int i = 0; i < 16; i++) acc[i] = 0.f;
#pragma unroll 4
    for (int d = 0; d < 64; d++) {
        float kv = kt[c][d];
#pragma unroll
        for (int i = 0; i < 16; i++) acc[i] += kv * qt[br + i][d];
    }
#pragma unroll
    for (int i = 0; i < 16; i++)
        kpart[(size_t)ds * 294912 + ((size_t)m * B + br + i) * C + c0 + c] = acc[i];
    if (cx == 0 && t < 64) {
        float s = 0.f;
        const float* kbp = kb + (size_t)m * C + d0;
        for (int d = 0; d < 64; d++) s += qt[t][d] * kbp[d];
        qkb_part[((size_t)m * 8 + ds) * B + t] = s;
    }
}

// qk = sum_ds kpart ; block 0 also reduces qkb_part -> qkb
__global__ __launch_bounds__(256) void k_kreduce(const float4* kpart, const float* qkb_part,
                                                 float4* qk, float* qkb) {
    int t = threadIdx.x;
    int i = blockIdx.x * 256 + t;
    float4 s = kpart[i];
#pragma unroll
    for (int ks = 1; ks < 8; ks++) {
        float4 v = kpart[(size_t)ks * 73728 + i];
        s.x += v.x; s.y += v.y; s.z += v.z; s.w += v.w;
    }
    qk[i] = s;
    if (blockIdx.x == 0) {
        for (int row = t; row < 576; row += 256) {
            int m = row >> 6, b = row & 63;
            float v = 0.f;
#pragma unroll
            for (int ds = 0; ds < 8; ds++) v += qkb_part[((size_t)m * 8 + ds) * B + b];
            qkb[row] = v;
        }
    }
}

// logits v2: grid (B, 3, 4) x 256; 64 tokens/block; 8 lanes per token.
// Q6 (3 qk rows + 3 raw g rows) staged in LDS; g-norm folded into final coefficient.
__global__ __launch_bounds__(256) void k_logits(const float* p0, const float* p1, const float* p2,
                                                const float* qk, const float* qkb,
                                                const float* g0, const float* g1, const float* g2,
                                                float* lgt) {
    int b = blockIdx.x, mi = blockIdx.y, ns = blockIdx.z;
    int t = threadIdx.x, w = t >> 6, l = t & 63;
    const float* p = (mi == 0) ? p0 : (mi == 1 ? p1 : p2);
    __shared__ float q6[6][512];
    __shared__ float ginv_s[3];
    for (int idx = t; idx < 768; idx += 256) {
        int row = idx >> 7, c4 = idx & 127;
        const float4* src;
        if (row < 3) {
            src = (const float4*)(qk + ((size_t)(3 * mi + row) * B + b) * C);
        } else {
            int gi = guide_of(3 * mi + row - 3);
            const float* graw = (gi == 0) ? g0 : (gi == 1 ? g1 : g2);
            src = (const float4*)(graw + (size_t)b * C);
        }
        ((float4*)q6[row])[c4] = src[c4];
    }
    __syncthreads();
    if (w < 3) {
        const float4* r4 = (const float4*)q6[3 + w];
        float4 a = r4[l * 2], bb = r4[l * 2 + 1];
        float n2 = dot4(a, a) + dot4(bb, bb);
#pragma unroll
        for (int mm = 1; mm < 64; mm <<= 1) n2 += __shfl_xor(n2, mm);
        if (l == 0) ginv_s[w] = 1.0f / fmaxf(sqrtf(n2), 1e-8f);
    }
    __syncthreads();
    float qkbv[3];
#pragma unroll
    for (int j = 0; j < 3; j++) qkbv[j] = qkb[(3 * mi + j) * B + b];
    const float4* pbase = (const float4*)(p + (size_t)b * N * C);
    const float SCALE = 0.044194173824159216f;  // 512^-0.5
    float* L = lgt + (size_t)(mi * B + b) * 3 * N;
    int s = l & 7, tl = l >> 3;
    const float4* Q0 = (const float4*)q6[0];
    const float4* Q1 = (const float4*)q6[1];
    const float4* Q2 = (const float4*)q6[2];
    const float4* G0 = (const float4*)q6[3];
    const float4* G1 = (const float4*)q6[4];
    const float4* G2 = (const float4*)q6[5];
#pragma unroll
    for (int pass = 0; pass < 2; pass++) {
        int n = ns * 64 + w * 16 + pass * 8 + tl;
        const float4* prow = pbase + (size_t)n * 128;
        float pp = 0.f, dj0 = 0.f, dj1 = 0.f, dj2 = 0.f, cj0 = 0.f, cj1 = 0.f, cj2 = 0.f;
#pragma unroll
        for (int i = 0; i < 16; i++) {
            int o = s + 8 * i;
            float4 pv = prow[o];
            pp  += dot4(pv, pv);
            dj0 += dot4(pv, Q0[o]);
            dj1 += dot4(pv, Q1[o]);
            dj2 += dot4(pv, Q2[o]);
            cj0 += dot4(pv, G0[o]);
            cj1 += dot4(pv, G1[o]);
            cj2 += dot4(pv, G2[o]);
        }
#pragma unroll
        for (int mm = 1; mm < 8; mm <<= 1) {
            pp  += __shfl_xor(pp, mm);
            dj0 += __shfl_xor(dj0, mm);
            dj1 += __shfl_xor(dj1, mm);
            dj2 += __shfl_xor(dj2, mm);
            cj0 += __shfl_xor(cj0, mm);
            cj1 += __shfl_xor(cj1, mm);
            cj2 += __shfl_xor(cj2, mm);
        }
        if (s == 0) {
            float rn = fmaxf(sqrtf(pp), 1e-8f);
            float ic = 1.0f / (rn * 0.3f);
            L[0 * N + n] = (dj0 + qkbv[0]) * SCALE + cj0 * ginv_s[0] * ic;
            L[1 * N + n] = (dj1 + qkbv[1]) * SCALE + cj1 * ginv_s[1] * ic;
            L[2 * N + n] = (dj2 + qkbv[2]) * SCALE + cj2 * ginv_s[2] * ic;
        }
    }
}

// finish (fused adaptive-weight MLP + score): per (mi,b)
__global__ __launch_bounds__(256) void k_finish(const float* lgt, const float* h1part,
                                                const float* b1, const float* lng, const float* lnb,
                                                const float* w2, const float* b2,
                                                const float* w3, const float* b3,
                                                float* msk, float* out) {
    int b = blockIdx.x, mi = blockIdx.y, t = threadIdx.x;
    __shared__ float h1[256];
    __shared__ float h2p[4][64];
    __shared__ float h2[64];
    __shared__ float red[4];
    __shared__ float wjs[3];
    __shared__ float sc[256];
    __shared__ float thr_s;
    // --- MLP phase ---
    float a1 = b1[mi * 256 + t];
#pragma unroll
    for (int ks = 0; ks < 12; ks++) a1 += h1part[(((size_t)ks * 3 + mi) * B + b) * 256 + t];
    float total = breduce_sum<4>(a1, red, t);
    float mean = total * (1.0f / 256.0f);
    float dv = a1 - mean;
    float vtot = breduce_sum<4>(dv * dv, red, t);
    float var = vtot * (1.0f / 256.0f);
    float x = dv / sqrtf(var + 1e-5f) * lng[mi * 256 + t] + lnb[mi * 256 + t];
    x = 0.5f * x * (1.0f + erff(x * 0.70710678118654752f));
    h1[t] = x;
    __syncthreads();
    {
        int col = t & 63, sl = t >> 6;  // 4 slices of 64
        float a2 = 0.f;
        const float* W2 = w2 + (size_t)mi * 256 * 64 + col;
#pragma unroll 8
        for (int e = sl * 64; e < sl * 64 + 64; e++) a2 += h1[e] * W2[(size_t)e * 64];
        h2p[sl][col] = a2;
    }
    __syncthreads();
    if (t < 64) {
        float a2 = b2[mi * 64 + t];
#pragma unroll
        for (int s2 = 0; s2 < 4; s2++) a2 += h2p[s2][t];
        a2 = 0.5f * a2 * (1.0f + erff(a2 * 0.70710678118654752f));
        h2[t] = a2;
    }
    __syncthreads();
    if (t == 0) {
        float l3[3];
        for (int j = 0; j < 3; j++) {
            float a3 = b3[mi * 3 + j];
            for (int e = 0; e < 64; e++) a3 += h2[e] * w3[((size_t)mi * 64 + e) * 3 + j];
            l3[j] = a3;
        }
        float mx = fmaxf(l3[0], fmaxf(l3[1], l3[2]));
        float e0 = expf(l3[0] - mx), e1 = expf(l3[1] - mx), e2 = expf(l3[2] - mx);
        float inv = 1.0f / (e0 + e1 + e2);
        wjs[0] = e0 * inv; wjs[1] = e1 * inv; wjs[2] = e2 * inv;
    }
    __syncthreads();
    // --- score phase ---
    const float* L = lgt + (size_t)(mi * B + b) * 3 * N;
    float score = 0.f;
    for (int j = 0; j < 3; j++) {
        float v = L[j * N + t];
        float mx = breduce_max<4>(v, red, t);
        float e = expf(v - mx);
        float s = breduce_sum<4>(e, red, t);
        float pr = e / s;
        float tot2 = breduce_sum<4>(pr, red, t);
        float mean2 = tot2 * (1.0f / 256.0f);
        float dv2 = pr - mean2;
        float vtot2 = breduce_sum<4>(dv2 * dv2, red, t);
        float sd = sqrtf(vtot2 * (1.0f / 255.0f)) + 1e-5f;
        float z = dv2 / sd;
        float sg = 1.0f / (1.0f + expf(-z));
        score += wjs[j] * sg;
    }
    sc[t] = score;
    __syncthreads();
    {
        int cl = 0, ce = 0;
        for (int m2 = 0; m2 < N; m2++) {
            float v2 = sc[m2];
            cl += (v2 < score) ? 1 : 0;
            ce += (v2 == score) ? 1 : 0;
        }
        if (cl <= 102 && 102 < cl + ce) thr_s = score;
    }
    __syncthreads();
    float thr = thr_s;
    float mk = 1.0f / (1.0f + expf(-(score - thr) * (1.0f / 0.3f)));
    msk[((size_t)mi * B + b) * N + t] = mk;
    out[(size_t)3 * B * N * C + ((size_t)mi * B + b) * N + t] = mk;
}

// scale: elementwise tokens * mask, grid-stride float4, nontemporal stores
__global__ __launch_bounds__(256) void k_scale(const float* p0, const float* p1, const float* p2,
                                               const float* msk, float* out) {
    const int TOT = 3 * B * N * C / 4;  // 6291456
    const float4* pb[3] = {(const float4*)p0, (const float4*)p1, (const float4*)p2};
    nfloat4* o4 = (nfloat4*)out;
    for (int idx = blockIdx.x * 256 + threadIdx.x; idx < TOT; idx += gridDim.x * 256) {
        int mi = idx >> 21;                 // B*N*C/4 = 2^21 per modality
        int r = idx & ((1 << 21) - 1);
        float4 v = pb[mi][r];
        float mkv = msk[(mi << 14) + (r >> 7)];  // 128 float4 per token
        nfloat4 nv;
        nv.x = v.x * mkv; nv.y = v.y * mkv; nv.z = v.z * mkv; nv.w = v.w * mkv;
        __builtin_nontemporal_store(nv, o4 + idx);
    }
}

extern "C" void kernel_launch(void* const* d_in, const int* in_sizes, int n_in,
                              void* d_out, int out_size, void* d_ws, size_t ws_size,
                              hipStream_t stream) {
    const float* rgb   = (const float*)d_in[0];
    const float* nir   = (const float*)d_in[1];
    const float* tir   = (const float*)d_in[2];
    const float* rgb_g = (const float*)d_in[3];
    const float* nir_g = (const float*)d_in[4];
    const float* tir_g = (const float*)d_in[5];
    const float* attn_qw = (const float*)d_in[6];
    const float* attn_qb = (const float*)d_in[7];
    const float* attn_kw = (const float*)d_in[8];
    const float* attn_kb = (const float*)d_in[9];
    const float* mlp_w1 = (const float*)d_in[10];
    const float* mlp_b1 = (const float*)d_in[11];
    const float* ln_g = (const float*)d_in[12];
    const float* ln_b = (const float*)d_in[13];
    const float* mlp_w2 = (const float*)d_in[14];
    const float* mlp_b2 = (const float*)d_in[15];
    const float* mlp_w3 = (const float*)d_in[16];
    const float* mlp_b3 = (const float*)d_in[17];
    float* out = (float*)d_out;

    float* ws = (float*)d_ws;
    // layout (floats):
    float* part     = ws;                // 8*294912 = 2359296
    float* kpart    = ws + 2359296;      // 2359296
    float* qk       = ws + 4718592;      // 294912
    float* qkb      = ws + 5013504;      // 576 -> pad 1024
    float* qkb_part = ws + 5014528;      // 9*8*64 = 4608
    float* h1part   = ws + 5019136;      // 12*3*64*256 = 589824
    float* lgt      = ws + 5608960;      // 3*64*3*256 = 147456
    float* msk      = ws + 5756416;      // 49152
    // total 5805568 floats = 23.2 MB

    k_proj_mlp<<<720, 256, 0, stream>>>(rgb_g, nir_g, tir_g, attn_qw, mlp_w1, part, h1part);
    k_kproj<<<dim3(8, 9, 8), 256, 0, stream>>>(attn_kw, part, attn_qb, attn_kb, kpart, qkb_part);
    k_kreduce<<<288, 256, 0, stream>>>((const float4*)kpart, qkb_part, (float4*)qk, qkb);
    k_logits<<<dim3(B, 3, 4), 256, 0, stream>>>(rgb, nir, tir, qk, qkb,
                                                rgb_g, nir_g, tir_g, lgt);
    k_finish<<<dim3(B, 3), 256, 0, stream>>>(lgt, h1part, mlp_b1, ln_g, ln_b,
                                             mlp_w2, mlp_b2, mlp_w3, mlp_b3, msk, out);
    k_scale<<<2048, 256, 0, stream>>>(rgb, nir, tir, msk, (float*)out);
}

// Round 7
// 115.133 us; speedup vs baseline: 3.3144x; 1.0480x over previous
//
#include <hip/hip_runtime.h>
#include <math.h>

#define B 64
#define N 256
#define C 512

typedef float nfloat4 __attribute__((ext_vector_type(4)));

// guide modality for module m = 3*mi + j
__device__ __forceinline__ int guide_of(int m) {
    int mi = m / 3, j = m % 3;
    return (j == 0) ? mi : (j == 1 ? ((mi == 0) ? 1 : 0) : ((mi == 2) ? 1 : 2));
}

template<int NW>
__device__ __forceinline__ float breduce_sum(float v, volatile float* red, int t) {
    int w = t >> 6, l = t & 63;
#pragma unroll
    for (int mm = 1; mm < 64; mm <<= 1) v += __shfl_xor(v, mm);
    __syncthreads();
    if (l == 0) red[w] = v;
    __syncthreads();
    float s = red[0];
#pragma unroll
    for (int i = 1; i < NW; i++) s += red[i];
    return s;
}

template<int NW>
__device__ __forceinline__ float breduce_max(float v, volatile float* red, int t) {
    int w = t >> 6, l = t & 63;
#pragma unroll
    for (int mm = 1; mm < 64; mm <<= 1) v = fmaxf(v, __shfl_xor(v, mm));
    __syncthreads();
    if (l == 0) red[w] = v;
    __syncthreads();
    float s = red[0];
#pragma unroll
    for (int i = 1; i < NW; i++) s = fmaxf(s, red[i]);
    return s;
}

__device__ __forceinline__ float dot4(float4 a, float4 b) {
    return a.x * b.x + a.y * b.y + a.z * b.z + a.w * b.w;
}

// Fused: qproj partials (blocks 0..575) + mlp fc1 tiles (blocks 576..719)
__global__ __launch_bounds__(256) void k_proj_mlp(const float* g0, const float* g1, const float* g2,
                                                  const float* qw, const float* w1,
                                                  float* part, float* h1part) {
    int bid = blockIdx.x;
    int t = threadIdx.x;
    __shared__ float gt[64 * 128];
    if (bid < 576) {
        int cx = bid & 7, m = (bid >> 3) % 9, ks = bid / 72;
        int c0 = cx * 64, e0 = ks * 64;
        int gi = guide_of(m);
        const float* g = (gi == 0) ? g0 : (gi == 1 ? g1 : g2);
        for (int idx = t; idx < 1024; idx += 256) {
            int r = idx >> 4, c4 = idx & 15;
            ((float4*)&gt[r * 128])[c4] = ((const float4*)(g + (size_t)r * C + e0))[c4];
        }
        __syncthreads();
        int c = c0 + (t & 63);
        int br = (t >> 6) * 16;
        float acc[16];
#pragma unroll
        for (int i = 0; i < 16; i++) acc[i] = 0.f;
        const float* W = qw + (size_t)m * C * C + (size_t)e0 * C + c;
#pragma unroll 4
        for (int e = 0; e < 64; e++) {
            float wv = W[(size_t)e * C];
#pragma unroll
            for (int i = 0; i < 16; i++) acc[i] += gt[(br + i) * 128 + e] * wv;
        }
#pragma unroll
        for (int i = 0; i < 16; i++)
            part[(size_t)ks * 294912 + ((size_t)m * B + br + i) * C + c] = acc[i];
    } else {
        int r = bid - 576;  // 0..143 : (cx=4, mi=3, ks=12)
        int cx = r & 3, mi = (r >> 2) % 3, ks = r / 12;
        int e0 = ks * 128;
        const float* g = (e0 < 512) ? g0 : (e0 < 1024 ? g1 : g2);
        int eo = e0 & 511;
        for (int idx = t; idx < 2048; idx += 256) {
            int rr = idx >> 5, c4 = idx & 31;
            ((float4*)&gt[rr * 128])[c4] = ((const float4*)(g + (size_t)rr * C + eo))[c4];
        }
        __syncthreads();
        int c = cx * 64 + (t & 63);
        int br = (t >> 6) * 16;
        float acc[16];
#pragma unroll
        for (int i = 0; i < 16; i++) acc[i] = 0.f;
        const float* W = w1 + ((size_t)mi * 1536 + e0) * 256 + c;
#pragma unroll 4
        for (int e = 0; e < 128; e++) {
            float wv = W[(size_t)e * 256];
#pragma unroll
            for (int i = 0; i < 16; i++) acc[i] += gt[(br + i) * 128 + e] * wv;
        }
#pragma unroll
        for (int i = 0; i < 16; i++)
            h1part[(((size_t)ks * 3 + mi) * B + br + i) * 256 + c] = acc[i];
    }
}

// kpart[ds][m][b][c] = sum_{d in slice ds} kw[m,c,d] * q[m,b,d]
// q inline-reduced from part; qkb_part computed by cx==0 blocks.
__global__ __launch_bounds__(256) void k_kproj(const float* kw, const float* part,
                                               const float* qb, const float* kb,
                                               float* kpart, float* qkb_part) {
    int cx = blockIdx.x, m = blockIdx.y, ds = blockIdx.z;
    int t = threadIdx.x;
    int c0 = cx * 64, d0 = ds * 64;
    __shared__ float kt[64][65];  // [c][d], padded
    __shared__ float qt[64][64];  // [b][d]
    for (int idx = t; idx < 1024; idx += 256) {
        int r = idx >> 4, c4 = idx & 15;
        float4 kv4 = *(const float4*)(kw + ((size_t)m * C + c0 + r) * C + d0 + c4 * 4);
        kt[r][c4 * 4 + 0] = kv4.x; kt[r][c4 * 4 + 1] = kv4.y;
        kt[r][c4 * 4 + 2] = kv4.z; kt[r][c4 * 4 + 3] = kv4.w;
        float4 s = *(const float4*)(qb + (size_t)m * C + d0 + c4 * 4);
        const float* pp = part + ((size_t)m * B + r) * C + d0 + c4 * 4;
#pragma unroll
        for (int ks = 0; ks < 8; ks++) {
            float4 v = *(const float4*)(pp + (size_t)ks * 294912);
            s.x += v.x; s.y += v.y; s.z += v.z; s.w += v.w;
        }
        ((float4*)qt[r])[c4] = s;
    }
    __syncthreads();
    int c = t & 63;
    int br = (t >> 6) * 16;
    float acc[16];
#pragma unroll
    for (int i = 0; i < 16; i++) acc[i] = 0.f;
#pragma unroll 4
    for (int d = 0; d < 64; d++) {
        float kv = kt[c][d];
#pragma unroll
        for (int i = 0; i < 16; i++) acc[i] += kv * qt[br + i][d];
    }
#pragma unroll
    for (int i = 0; i < 16; i++)
        kpart[(size_t)ds * 294912 + ((size_t)m * B + br + i) * C + c0 + c] = acc[i];
    if (cx == 0 && t < 64) {
        float s = 0.f;
        const float* kbp = kb + (size_t)m * C + d0;
        for (int d = 0; d < 64; d++) s += qt[t][d] * kbp[d];
        qkb_part[((size_t)m * 8 + ds) * B + t] = s;
    }
}

// logits v3: grid (B, 3, 4) x 256; fused kpart/qkb reduce in staging.
__global__ __launch_bounds__(256) void k_logits(const float* p0, const float* p1, const float* p2,
                                                const float* kpart, const float* qkb_part,
                                                const float* g0, const float* g1, const float* g2,
                                                float* lgt) {
    int b = blockIdx.x, mi = blockIdx.y, ns = blockIdx.z;
    int t = threadIdx.x, w = t >> 6, l = t & 63;
    const float* p = (mi == 0) ? p0 : (mi == 1 ? p1 : p2);
    __shared__ float q6[6][512];
    __shared__ float ginv_s[3];
    __shared__ float qkb_s[3];
    for (int idx = t; idx < 768; idx += 256) {
        int row = idx >> 7, c4 = idx & 127;
        float4 v;
        if (row < 3) {
            int m = 3 * mi + row;
            const float4* kp = (const float4*)kpart + ((size_t)m * B + b) * 128 + c4;
            v = kp[0];
#pragma unroll
            for (int ds = 1; ds < 8; ds++) {
                float4 u = kp[(size_t)ds * 73728];
                v.x += u.x; v.y += u.y; v.z += u.z; v.w += u.w;
            }
        } else {
            int gi = guide_of(3 * mi + row - 3);
            const float* graw = (gi == 0) ? g0 : (gi == 1 ? g1 : g2);
            v = ((const float4*)(graw + (size_t)b * C))[c4];
        }
        ((float4*)q6[row])[c4] = v;
    }
    if (t < 3) {
        int m = 3 * mi + t;
        float s = 0.f;
#pragma unroll
        for (int ds = 0; ds < 8; ds++) s += qkb_part[((size_t)m * 8 + ds) * B + b];
        qkb_s[t] = s;
    }
    __syncthreads();
    if (w < 3) {
        const float4* r4 = (const float4*)q6[3 + w];
        float4 a = r4[l * 2], bb = r4[l * 2 + 1];
        float n2 = dot4(a, a) + dot4(bb, bb);
#pragma unroll
        for (int mm = 1; mm < 64; mm <<= 1) n2 += __shfl_xor(n2, mm);
        if (l == 0) ginv_s[w] = 1.0f / fmaxf(sqrtf(n2), 1e-8f);
    }
    __syncthreads();
    float qkbv[3];
#pragma unroll
    for (int j = 0; j < 3; j++) qkbv[j] = qkb_s[j];
    const float4* pbase = (const float4*)(p + (size_t)b * N * C);
    const float SCALE = 0.044194173824159216f;  // 512^-0.5
    float* L = lgt + (size_t)(mi * B + b) * 3 * N;
    int s = l & 7, tl = l >> 3;
    const float4* Q0 = (const float4*)q6[0];
    const float4* Q1 = (const float4*)q6[1];
    const float4* Q2 = (const float4*)q6[2];
    const float4* G0 = (const float4*)q6[3];
    const float4* G1 = (const float4*)q6[4];
    const float4* G2 = (const float4*)q6[5];
#pragma unroll
    for (int pass = 0; pass < 2; pass++) {
        int n = ns * 64 + w * 16 + pass * 8 + tl;
        const float4* prow = pbase + (size_t)n * 128;
        float pp = 0.f, dj0 = 0.f, dj1 = 0.f, dj2 = 0.f, cj0 = 0.f, cj1 = 0.f, cj2 = 0.f;
#pragma unroll
        for (int i = 0; i < 16; i++) {
            int o = s + 8 * i;
            float4 pv = prow[o];
            pp  += dot4(pv, pv);
            dj0 += dot4(pv, Q0[o]);
            dj1 += dot4(pv, Q1[o]);
            dj2 += dot4(pv, Q2[o]);
            cj0 += dot4(pv, G0[o]);
            cj1 += dot4(pv, G1[o]);
            cj2 += dot4(pv, G2[o]);
        }
#pragma unroll
        for (int mm = 1; mm < 8; mm <<= 1) {
            pp  += __shfl_xor(pp, mm);
            dj0 += __shfl_xor(dj0, mm);
            dj1 += __shfl_xor(dj1, mm);
            dj2 += __shfl_xor(dj2, mm);
            cj0 += __shfl_xor(cj0, mm);
            cj1 += __shfl_xor(cj1, mm);
            cj2 += __shfl_xor(cj2, mm);
        }
        if (s == 0) {
            float rn = fmaxf(sqrtf(pp), 1e-8f);
            float ic = 1.0f / (rn * 0.3f);
            L[0 * N + n] = (dj0 + qkbv[0]) * SCALE + cj0 * ginv_s[0] * ic;
            L[1 * N + n] = (dj1 + qkbv[1]) * SCALE + cj1 * ginv_s[1] * ic;
            L[2 * N + n] = (dj2 + qkbv[2]) * SCALE + cj2 * ginv_s[2] * ic;
        }
    }
}

// finscale: grid (B, 3, 4) x 256. Each block redundantly computes the full
// MLP+score+quantile for its (mi,b) (identical fp order -> identical thr across
// the 4 blocks), writes its 64-token mask range, and rescales its patch slab.
__global__ __launch_bounds__(256) void k_finscale(const float* lgt, const float* h1part,
                                                  const float* b1, const float* lng, const float* lnb,
                                                  const float* w2, const float* b2,
                                                  const float* w3, const float* b3,
                                                  const float* p0, const float* p1, const float* p2,
                                                  float* out) {
    int b = blockIdx.x, mi = blockIdx.y, ns = blockIdx.z, t = threadIdx.x;
    __shared__ float h1[256];
    __shared__ float h2p[4][64];
    __shared__ float h2[64];
    __shared__ float red[4];
    __shared__ float wjs[3];
    __shared__ float sc[256];
    __shared__ float mks[256];
    __shared__ float thr_s;
    // --- MLP phase ---
    float a1 = b1[mi * 256 + t];
#pragma unroll
    for (int ks = 0; ks < 12; ks++) a1 += h1part[(((size_t)ks * 3 + mi) * B + b) * 256 + t];
    float total = breduce_sum<4>(a1, red, t);
    float mean = total * (1.0f / 256.0f);
    float dv = a1 - mean;
    float vtot = breduce_sum<4>(dv * dv, red, t);
    float var = vtot * (1.0f / 256.0f);
    float x = dv / sqrtf(var + 1e-5f) * lng[mi * 256 + t] + lnb[mi * 256 + t];
    x = 0.5f * x * (1.0f + erff(x * 0.70710678118654752f));
    h1[t] = x;
    __syncthreads();
    {
        int col = t & 63, sl = t >> 6;  // 4 slices of 64
        float a2 = 0.f;
        const float* W2 = w2 + (size_t)mi * 256 * 64 + col;
#pragma unroll 8
        for (int e = sl * 64; e < sl * 64 + 64; e++) a2 += h1[e] * W2[(size_t)e * 64];
        h2p[sl][col] = a2;
    }
    __syncthreads();
    if (t < 64) {
        float a2 = b2[mi * 64 + t];
#pragma unroll
        for (int s2 = 0; s2 < 4; s2++) a2 += h2p[s2][t];
        a2 = 0.5f * a2 * (1.0f + erff(a2 * 0.70710678118654752f));
        h2[t] = a2;
    }
    __syncthreads();
    if (t == 0) {
        float l3[3];
        for (int j = 0; j < 3; j++) {
            float a3 = b3[mi * 3 + j];
            for (int e = 0; e < 64; e++) a3 += h2[e] * w3[((size_t)mi * 64 + e) * 3 + j];
            l3[j] = a3;
        }
        float mx = fmaxf(l3[0], fmaxf(l3[1], l3[2]));
        float e0 = expf(l3[0] - mx), e1 = expf(l3[1] - mx), e2 = expf(l3[2] - mx);
        float inv = 1.0f / (e0 + e1 + e2);
        wjs[0] = e0 * inv; wjs[1] = e1 * inv; wjs[2] = e2 * inv;
    }
    __syncthreads();
    // --- score phase ---
    const float* L = lgt + (size_t)(mi * B + b) * 3 * N;
    float score = 0.f;
    for (int j = 0; j < 3; j++) {
        float v = L[j * N + t];
        float mx = breduce_max<4>(v, red, t);
        float e = expf(v - mx);
        float s = breduce_sum<4>(e, red, t);
        float pr = e / s;
        float tot2 = breduce_sum<4>(pr, red, t);
        float mean2 = tot2 * (1.0f / 256.0f);
        float dv2 = pr - mean2;
        float vtot2 = breduce_sum<4>(dv2 * dv2, red, t);
        float sd = sqrtf(vtot2 * (1.0f / 255.0f)) + 1e-5f;
        float z = dv2 / sd;
        float sg = 1.0f / (1.0f + expf(-z));
        score += wjs[j] * sg;
    }
    sc[t] = score;
    __syncthreads();
    {
        int cl = 0, ce = 0;
        for (int m2 = 0; m2 < N; m2++) {
            float v2 = sc[m2];
            cl += (v2 < score) ? 1 : 0;
            ce += (v2 == score) ? 1 : 0;
        }
        if (cl <= 102 && 102 < cl + ce) thr_s = score;
    }
    __syncthreads();
    float thr = thr_s;
    float mk = 1.0f / (1.0f + expf(-(score - thr) * (1.0f / 0.3f)));
    mks[t] = mk;
    if ((t >> 6) == ns)
        out[(size_t)3 * B * N * C + ((size_t)mi * B + b) * N + t] = mk;
    __syncthreads();
    // --- scale phase: 64 tokens (ns*64..), 8192 float4 ---
    const float* p = (mi == 0) ? p0 : (mi == 1 ? p1 : p2);
    const float4* pslab = (const float4*)(p + (size_t)b * N * C + (size_t)ns * 64 * C);
    nfloat4* oslab = (nfloat4*)(out + (size_t)mi * B * N * C + (size_t)b * N * C
                                + (size_t)ns * 64 * C);
#pragma unroll 4
    for (int idx = t; idx < 8192; idx += 256) {
        float4 v = pslab[idx];
        float mkv = mks[ns * 64 + (idx >> 7)];
        nfloat4 nv;
        nv.x = v.x * mkv; nv.y = v.y * mkv; nv.z = v.z * mkv; nv.w = v.w * mkv;
        __builtin_nontemporal_store(nv, oslab + idx);
    }
}

extern "C" void kernel_launch(void* const* d_in, const int* in_sizes, int n_in,
                              void* d_out, int out_size, void* d_ws, size_t ws_size,
                              hipStream_t stream) {
    const float* rgb   = (const float*)d_in[0];
    const float* nir   = (const float*)d_in[1];
    const float* tir   = (const float*)d_in[2];
    const float* rgb_g = (const float*)d_in[3];
    const float* nir_g = (const float*)d_in[4];
    const float* tir_g = (const float*)d_in[5];
    const float* attn_qw = (const float*)d_in[6];
    const float* attn_qb = (const float*)d_in[7];
    const float* attn_kw = (const float*)d_in[8];
    const float* attn_kb = (const float*)d_in[9];
    const float* mlp_w1 = (const float*)d_in[10];
    const float* mlp_b1 = (const float*)d_in[11];
    const float* ln_g = (const float*)d_in[12];
    const float* ln_b = (const float*)d_in[13];
    const float* mlp_w2 = (const float*)d_in[14];
    const float* mlp_b2 = (const float*)d_in[15];
    const float* mlp_w3 = (const float*)d_in[16];
    const float* mlp_b3 = (const float*)d_in[17];
    float* out = (float*)d_out;

    float* ws = (float*)d_ws;
    // layout (floats):
    float* part     = ws;                // 8*294912 = 2359296
    float* kpart    = ws + 2359296;      // 2359296
    float* qkb_part = ws + 4718592;      // 9*8*64 = 4608 -> pad 5120
    float* h1part   = ws + 4723712;      // 12*3*64*256 = 589824
    float* lgt      = ws + 5313536;      // 3*64*3*256 = 147456
    // total 5460992 floats = 21.8 MB

    k_proj_mlp<<<720, 256, 0, stream>>>(rgb_g, nir_g, tir_g, attn_qw, mlp_w1, part, h1part);
    k_kproj<<<dim3(8, 9, 8), 256, 0, stream>>>(attn_kw, part, attn_qb, attn_kb, kpart, qkb_part);
    k_logits<<<dim3(B, 3, 4), 256, 0, stream>>>(rgb, nir, tir, kpart, qkb_part,
                                                rgb_g, nir_g, tir_g, lgt);
    k_finscale<<<dim3(B, 3, 4), 256, 0, stream>>>(lgt, h1part, mlp_b1, ln_g, ln_b,
                                                  mlp_w2, mlp_b2, mlp_w3, mlp_b3,
                                                  rgb, nir, tir, out);
}